// Round 1
// baseline (688.414 us; speedup 1.0000x reference)
//
#include <hip/hip_runtime.h>
#include <hip/hip_bf16.h>

#define DFEAT 128

// ---------------- CSR build ----------------

__global__ void count_kernel(const int* __restrict__ EI, int* __restrict__ deg_src,
                             int* __restrict__ cnt_dst, int nedges) {
    int e = blockIdx.x * blockDim.x + threadIdx.x;
    if (e >= nedges) return;
    int dst = EI[e];              // edge_index[0]
    int src = EI[nedges + e];     // edge_index[1]
    atomicAdd(&deg_src[src], 1);
    atomicAdd(&cnt_dst[dst], 1);
}

__global__ void dis_kernel(const int* __restrict__ deg, float* __restrict__ dis, int n) {
    int i = blockIdx.x * blockDim.x + threadIdx.x;
    if (i >= n) return;
    int d = deg[i];
    dis[i] = (d > 0) ? rsqrtf((float)d) : 0.0f;
}

// Block-level inclusive scan of cnt into offs[g+1]; per-block total into bsums.
__global__ __launch_bounds__(1024) void scan1_kernel(const int* __restrict__ cnt,
                                                     int* __restrict__ offs,
                                                     int* __restrict__ bsums, int n) {
    __shared__ int s[1024];
    int t = threadIdx.x;
    int g = blockIdx.x * 1024 + t;
    int v = (g < n) ? cnt[g] : 0;
    s[t] = v;
    __syncthreads();
    for (int off = 1; off < 1024; off <<= 1) {
        int add = (t >= off) ? s[t - off] : 0;
        __syncthreads();
        s[t] += add;
        __syncthreads();
    }
    if (g < n) offs[g + 1] = s[t];
    if (t == 1023) bsums[blockIdx.x] = s[1023];
}

// Exclusive scan of block sums (nb <= 64) with one wave.
__global__ void scan2_kernel(int* __restrict__ bsums, int nb) {
    int lane = threadIdx.x;  // blockDim = 64
    int v = (lane < nb) ? bsums[lane] : 0;
    for (int off = 1; off < 64; off <<= 1) {
        int t = __shfl_up(v, off);
        if (lane >= off) v += t;
    }
    int ex = __shfl_up(v, 1);
    if (lane == 0) ex = 0;
    if (lane < nb) bsums[lane] = ex;
}

__global__ __launch_bounds__(1024) void scan3_kernel(int* __restrict__ offs,
                                                     const int* __restrict__ bsums, int n) {
    int t = threadIdx.x;
    int b = blockIdx.x;
    int g = b * 1024 + t;
    int add = bsums[b];
    if (g < n) offs[g + 1] += add;
    if (b == 0 && t == 0) offs[0] = 0;
}

__global__ void fill_kernel(const int* __restrict__ EI, const int* __restrict__ offs,
                            int* __restrict__ cursor, const float* __restrict__ dis,
                            int* __restrict__ ssrc, float* __restrict__ snorm, int nedges) {
    int e = blockIdx.x * blockDim.x + threadIdx.x;
    if (e >= nedges) return;
    int dst = EI[e];
    int src = EI[nedges + e];
    int pos = atomicAdd(&cursor[dst], 1);
    int idx = offs[dst] + pos;
    ssrc[idx] = src;
    snorm[idx] = dis[src] * dis[dst];
}

// ---------------- GEMM: H[N,128] = X[N,128] @ W[128,128] ----------------
// Block = 256 threads, tile = 16 rows x 128 cols, thread (i,j) computes
// row i, cols j*8..j*8+7.

__global__ __launch_bounds__(256) void gemm_kernel(const float* __restrict__ X,
                                                   const float* __restrict__ W,
                                                   float* __restrict__ H, int nrows) {
    __shared__ float xs[16][132];  // pad 128->132: bank-conflict-free, 16B-aligned rows
    const int t = threadIdx.x;
    const int base = blockIdx.x * 16;

    // stage 16x128 x-tile: 512 float4, 2 per thread
    #pragma unroll
    for (int q = 0; q < 2; ++q) {
        int f4 = t * 2 + q;
        int r = f4 >> 5, c4 = f4 & 31;
        float4 v;
        if (base + r < nrows)
            v = *(const float4*)(X + (size_t)(base + r) * DFEAT + c4 * 4);
        else
            v = make_float4(0.f, 0.f, 0.f, 0.f);
        *(float4*)&xs[r][c4 * 4] = v;
    }
    __syncthreads();

    const int i = t >> 4, j = t & 15;
    float acc[8] = {0, 0, 0, 0, 0, 0, 0, 0};
    const float4* W4 = (const float4*)W;
    #pragma unroll 4
    for (int k = 0; k < DFEAT; ++k) {
        float a = xs[i][k];
        float4 w0 = W4[k * 32 + j * 2];
        float4 w1 = W4[k * 32 + j * 2 + 1];
        acc[0] += a * w0.x; acc[1] += a * w0.y; acc[2] += a * w0.z; acc[3] += a * w0.w;
        acc[4] += a * w1.x; acc[5] += a * w1.y; acc[6] += a * w1.z; acc[7] += a * w1.w;
    }
    if (base + i < nrows) {
        float* out = H + (size_t)(base + i) * DFEAT + j * 8;
        *(float4*)out = make_float4(acc[0], acc[1], acc[2], acc[3]);
        *(float4*)(out + 4) = make_float4(acc[4], acc[5], acc[6], acc[7]);
    }
}

// ---------------- Aggregation: one wave per dst node ----------------

__global__ __launch_bounds__(256) void agg_kernel(const float* __restrict__ H,
                                                  const int* __restrict__ offs,
                                                  const int* __restrict__ ssrc,
                                                  const float* __restrict__ snorm,
                                                  const float* __restrict__ bias,
                                                  float* __restrict__ OUT,
                                                  int do_relu, int nnodes) {
    int node = blockIdx.x * 4 + (threadIdx.x >> 6);
    int lane = threadIdx.x & 63;
    if (node >= nnodes) return;
    int s = offs[node];
    int e = offs[node + 1];
    float ax = 0.f, ay = 0.f;
    for (int idx = s; idx < e; ++idx) {
        int src = ssrc[idx];
        float nm = snorm[idx];
        float2 v = *(const float2*)&H[(size_t)src * DFEAT + lane * 2];
        ax += nm * v.x;
        ay += nm * v.y;
    }
    float2 b = *(const float2*)&bias[lane * 2];
    ax += b.x;
    ay += b.y;
    if (do_relu) { ax = fmaxf(ax, 0.f); ay = fmaxf(ay, 0.f); }
    *(float2*)&OUT[(size_t)node * DFEAT + lane * 2] = make_float2(ax, ay);
}

// ---------------- launch ----------------

extern "C" void kernel_launch(void* const* d_in, const int* in_sizes, int n_in,
                              void* d_out, int out_size, void* d_ws, size_t ws_size,
                              hipStream_t stream) {
    const float* x  = (const float*)d_in[0];
    const int*   EI = (const int*)d_in[1];
    const float* W0 = (const float*)d_in[2];
    const float* b0 = (const float*)d_in[3];
    const float* W1 = (const float*)d_in[4];
    const float* b1 = (const float*)d_in[5];
    const float* W2 = (const float*)d_in[6];
    const float* b2 = (const float*)d_in[7];
    float* out = (float*)d_out;

    const int N = in_sizes[0] / DFEAT;
    const int E = in_sizes[1] / 2;

    // workspace layout (256B aligned)
    char* w = (char*)d_ws;
    auto alloc = [&](size_t bytes) {
        void* p = (void*)w;
        w += (bytes + 255) & ~(size_t)255;
        return p;
    };
    int*   deg    = (int*)alloc((size_t)N * 4);
    int*   cnt    = (int*)alloc((size_t)N * 4);
    int*   offs   = (int*)alloc((size_t)(N + 1) * 4);
    int*   bsums  = (int*)alloc(64 * 4);
    int*   cursor = (int*)alloc((size_t)N * 4);
    float* dis    = (float*)alloc((size_t)N * 4);
    int*   ssrc   = (int*)alloc((size_t)E * 4);
    float* snorm  = (float*)alloc((size_t)E * 4);
    float* hbuf   = (float*)alloc((size_t)N * DFEAT * 4);
    float* abuf   = (float*)alloc((size_t)N * DFEAT * 4);

    hipMemsetAsync(deg, 0, (size_t)N * 4, stream);
    hipMemsetAsync(cnt, 0, (size_t)N * 4, stream);
    hipMemsetAsync(cursor, 0, (size_t)N * 4, stream);

    const int nb = (N + 1023) / 1024;

    count_kernel<<<(E + 255) / 256, 256, 0, stream>>>(EI, deg, cnt, E);
    dis_kernel<<<(N + 255) / 256, 256, 0, stream>>>(deg, dis, N);
    scan1_kernel<<<nb, 1024, 0, stream>>>(cnt, offs, bsums, N);
    scan2_kernel<<<1, 64, 0, stream>>>(bsums, nb);
    scan3_kernel<<<nb, 1024, 0, stream>>>(offs, bsums, N);
    fill_kernel<<<(E + 255) / 256, 256, 0, stream>>>(EI, offs, cursor, dis, ssrc, snorm, E);

    const int gemmGrid = (N + 15) / 16;
    const int aggGrid  = (N + 3) / 4;

    // layer 0: x -> hbuf -> abuf (relu)
    gemm_kernel<<<gemmGrid, 256, 0, stream>>>(x, W0, hbuf, N);
    agg_kernel<<<aggGrid, 256, 0, stream>>>(hbuf, offs, ssrc, snorm, b0, abuf, 1, N);
    // layer 1: abuf -> hbuf -> abuf (relu)
    gemm_kernel<<<gemmGrid, 256, 0, stream>>>(abuf, W1, hbuf, N);
    agg_kernel<<<aggGrid, 256, 0, stream>>>(hbuf, offs, ssrc, snorm, b1, abuf, 1, N);
    // layer 2: abuf -> hbuf -> d_out (no relu)
    gemm_kernel<<<gemmGrid, 256, 0, stream>>>(abuf, W2, hbuf, N);
    agg_kernel<<<aggGrid, 256, 0, stream>>>(hbuf, offs, ssrc, snorm, b2, out, 0, N);
}

// Round 2
// 430.636 us; speedup vs baseline: 1.5986x; 1.5986x over previous
//
#include <hip/hip_runtime.h>
#include <hip/hip_bf16.h>

#define DFEAT 128

// ---------------- CSR build ----------------

__global__ void count_kernel(const int* __restrict__ EI, int* __restrict__ deg_src,
                             int* __restrict__ cnt_dst, int nedges) {
    int e = blockIdx.x * blockDim.x + threadIdx.x;
    if (e >= nedges) return;
    int dst = EI[e];              // edge_index[0]
    int src = EI[nedges + e];     // edge_index[1]
    atomicAdd(&deg_src[src], 1);
    atomicAdd(&cnt_dst[dst], 1);
}

__global__ void dis_kernel(const int* __restrict__ deg, float* __restrict__ dis, int n) {
    int i = blockIdx.x * blockDim.x + threadIdx.x;
    if (i >= n) return;
    int d = deg[i];
    dis[i] = (d > 0) ? rsqrtf((float)d) : 0.0f;
}

// Block-level inclusive scan of cnt into offs[g+1]; per-block total into bsums.
__global__ __launch_bounds__(1024) void scan1_kernel(const int* __restrict__ cnt,
                                                     int* __restrict__ offs,
                                                     int* __restrict__ bsums, int n) {
    __shared__ int s[1024];
    int t = threadIdx.x;
    int g = blockIdx.x * 1024 + t;
    int v = (g < n) ? cnt[g] : 0;
    s[t] = v;
    __syncthreads();
    for (int off = 1; off < 1024; off <<= 1) {
        int add = (t >= off) ? s[t - off] : 0;
        __syncthreads();
        s[t] += add;
        __syncthreads();
    }
    if (g < n) offs[g + 1] = s[t];
    if (t == 1023) bsums[blockIdx.x] = s[1023];
}

// Exclusive scan of block sums (nb <= 64) with one wave.
__global__ void scan2_kernel(int* __restrict__ bsums, int nb) {
    int lane = threadIdx.x;  // blockDim = 64
    int v = (lane < nb) ? bsums[lane] : 0;
    for (int off = 1; off < 64; off <<= 1) {
        int t = __shfl_up(v, off);
        if (lane >= off) v += t;
    }
    int ex = __shfl_up(v, 1);
    if (lane == 0) ex = 0;
    if (lane < nb) bsums[lane] = ex;
}

__global__ __launch_bounds__(1024) void scan3_kernel(int* __restrict__ offs,
                                                     const int* __restrict__ bsums, int n) {
    int t = threadIdx.x;
    int b = blockIdx.x;
    int g = b * 1024 + t;
    int add = bsums[b];
    if (g < n) offs[g + 1] += add;
    if (b == 0 && t == 0) offs[0] = 0;
}

// Pack (src, norm) into one int2 per edge slot, dst-sorted via CSR cursor.
__global__ void fill_kernel(const int* __restrict__ EI, const int* __restrict__ offs,
                            int* __restrict__ cursor, const float* __restrict__ dis,
                            int2* __restrict__ edges, int nedges) {
    int e = blockIdx.x * blockDim.x + threadIdx.x;
    if (e >= nedges) return;
    int dst = EI[e];
    int src = EI[nedges + e];
    int pos = atomicAdd(&cursor[dst], 1);
    int idx = offs[dst] + pos;
    float nm = dis[src] * dis[dst];
    edges[idx] = make_int2(src, __float_as_int(nm));
}

// ---------------- GEMM: H[N,128] = X[N,128] @ W[128,128] ----------------
// Block = 256 threads, tile = 64 rows x 128 cols.
// Thread (i,j): i = t>>4 (0..15), j = t&15. Computes rows {i, i+16, i+32, i+48},
// cols j*8 .. j*8+7 -> acc[4][8] register tile.

__global__ __launch_bounds__(256) void gemm_kernel(const float* __restrict__ X,
                                                   const float* __restrict__ W,
                                                   float* __restrict__ H, int nrows) {
    __shared__ float xs[64][136];  // 136*4 = 544 B row stride: 16B-aligned, banks i*8 apart
    const int t = threadIdx.x;
    const int base = blockIdx.x * 64;

    // stage 64x128 x-tile: 2048 float4, 8 per thread, coalesced
    #pragma unroll
    for (int q = 0; q < 8; ++q) {
        int f4 = t + q * 256;
        int r = f4 >> 5, c4 = f4 & 31;
        float4 v = make_float4(0.f, 0.f, 0.f, 0.f);
        if (base + r < nrows)
            v = *(const float4*)(X + (size_t)(base + r) * DFEAT + c4 * 4);
        *(float4*)&xs[r][c4 * 4] = v;
    }
    __syncthreads();

    const int i = t >> 4, j = t & 15;
    float acc[4][8];
    #pragma unroll
    for (int r = 0; r < 4; ++r)
        #pragma unroll
        for (int c = 0; c < 8; ++c) acc[r][c] = 0.f;

    const float4* __restrict__ W4 = (const float4*)W;

    for (int k = 0; k < DFEAT; k += 4) {
        float4 a[4];
        #pragma unroll
        for (int r = 0; r < 4; ++r)
            a[r] = *(const float4*)&xs[i + r * 16][k];  // ds_read_b128, conflict-free
        #pragma unroll
        for (int kk = 0; kk < 4; ++kk) {
            float4 w0 = W4[(k + kk) * 32 + j * 2];
            float4 w1 = W4[(k + kk) * 32 + j * 2 + 1];
            #pragma unroll
            for (int r = 0; r < 4; ++r) {
                float av = (kk == 0) ? a[r].x : (kk == 1) ? a[r].y : (kk == 2) ? a[r].z : a[r].w;
                acc[r][0] += av * w0.x; acc[r][1] += av * w0.y;
                acc[r][2] += av * w0.z; acc[r][3] += av * w0.w;
                acc[r][4] += av * w1.x; acc[r][5] += av * w1.y;
                acc[r][6] += av * w1.z; acc[r][7] += av * w1.w;
            }
        }
    }

    #pragma unroll
    for (int r = 0; r < 4; ++r) {
        int row = base + i + r * 16;
        if (row < nrows) {
            float* out = H + (size_t)row * DFEAT + j * 8;
            *(float4*)out = make_float4(acc[r][0], acc[r][1], acc[r][2], acc[r][3]);
            *(float4*)(out + 4) = make_float4(acc[r][4], acc[r][5], acc[r][6], acc[r][7]);
        }
    }
}

// ---------------- Aggregation: one wave per dst node ----------------

__global__ __launch_bounds__(256) void agg_kernel(const float* __restrict__ H,
                                                  const int* __restrict__ offs,
                                                  const int2* __restrict__ edges,
                                                  const float* __restrict__ bias,
                                                  float* __restrict__ OUT,
                                                  int do_relu, int nnodes) {
    int node = blockIdx.x * 4 + (threadIdx.x >> 6);
    int lane = threadIdx.x & 63;
    if (node >= nnodes) return;
    int s = offs[node];
    int e = offs[node + 1];
    float ax = 0.f, ay = 0.f, bx = 0.f, by = 0.f;
    int idx = s;
    for (; idx + 2 <= e; idx += 2) {
        int2 e0 = edges[idx];
        int2 e1 = edges[idx + 1];
        float nm0 = __int_as_float(e0.y);
        float nm1 = __int_as_float(e1.y);
        float2 v0 = *(const float2*)&H[(size_t)e0.x * DFEAT + lane * 2];
        float2 v1 = *(const float2*)&H[(size_t)e1.x * DFEAT + lane * 2];
        ax += nm0 * v0.x; ay += nm0 * v0.y;
        bx += nm1 * v1.x; by += nm1 * v1.y;
    }
    if (idx < e) {
        int2 e0 = edges[idx];
        float nm0 = __int_as_float(e0.y);
        float2 v0 = *(const float2*)&H[(size_t)e0.x * DFEAT + lane * 2];
        ax += nm0 * v0.x; ay += nm0 * v0.y;
    }
    ax += bx; ay += by;
    float2 b = *(const float2*)&bias[lane * 2];
    ax += b.x;
    ay += b.y;
    if (do_relu) { ax = fmaxf(ax, 0.f); ay = fmaxf(ay, 0.f); }
    *(float2*)&OUT[(size_t)node * DFEAT + lane * 2] = make_float2(ax, ay);
}

// ---------------- launch ----------------

extern "C" void kernel_launch(void* const* d_in, const int* in_sizes, int n_in,
                              void* d_out, int out_size, void* d_ws, size_t ws_size,
                              hipStream_t stream) {
    const float* x  = (const float*)d_in[0];
    const int*   EI = (const int*)d_in[1];
    const float* W0 = (const float*)d_in[2];
    const float* b0 = (const float*)d_in[3];
    const float* W1 = (const float*)d_in[4];
    const float* b1 = (const float*)d_in[5];
    const float* W2 = (const float*)d_in[6];
    const float* b2 = (const float*)d_in[7];
    float* out = (float*)d_out;

    const int N = in_sizes[0] / DFEAT;
    const int E = in_sizes[1] / 2;

    // workspace layout (256B aligned)
    char* w = (char*)d_ws;
    auto alloc = [&](size_t bytes) {
        void* p = (void*)w;
        w += (bytes + 255) & ~(size_t)255;
        return p;
    };
    int*   deg    = (int*)alloc((size_t)N * 4);
    int*   cnt    = (int*)alloc((size_t)N * 4);
    int*   offs   = (int*)alloc((size_t)(N + 1) * 4);
    int*   bsums  = (int*)alloc(64 * 4);
    int*   cursor = (int*)alloc((size_t)N * 4);
    float* dis    = (float*)alloc((size_t)N * 4);
    int2*  edges  = (int2*)alloc((size_t)E * 8);
    float* hbuf   = (float*)alloc((size_t)N * DFEAT * 4);
    float* abuf   = (float*)alloc((size_t)N * DFEAT * 4);

    hipMemsetAsync(deg, 0, (size_t)N * 4, stream);
    hipMemsetAsync(cnt, 0, (size_t)N * 4, stream);
    hipMemsetAsync(cursor, 0, (size_t)N * 4, stream);

    const int nb = (N + 1023) / 1024;

    count_kernel<<<(E + 255) / 256, 256, 0, stream>>>(EI, deg, cnt, E);
    dis_kernel<<<(N + 255) / 256, 256, 0, stream>>>(deg, dis, N);
    scan1_kernel<<<nb, 1024, 0, stream>>>(cnt, offs, bsums, N);
    scan2_kernel<<<1, 64, 0, stream>>>(bsums, nb);
    scan3_kernel<<<nb, 1024, 0, stream>>>(offs, bsums, N);
    fill_kernel<<<(E + 255) / 256, 256, 0, stream>>>(EI, offs, cursor, dis, edges, E);

    const int gemmGrid = (N + 63) / 64;
    const int aggGrid  = (N + 3) / 4;

    // layer 0: x -> hbuf -> abuf (relu)
    gemm_kernel<<<gemmGrid, 256, 0, stream>>>(x, W0, hbuf, N);
    agg_kernel<<<aggGrid, 256, 0, stream>>>(hbuf, offs, edges, b0, abuf, 1, N);
    // layer 1: abuf -> hbuf -> abuf (relu)
    gemm_kernel<<<gemmGrid, 256, 0, stream>>>(abuf, W1, hbuf, N);
    agg_kernel<<<aggGrid, 256, 0, stream>>>(hbuf, offs, edges, b1, abuf, 1, N);
    // layer 2: abuf -> hbuf -> d_out (no relu)
    gemm_kernel<<<gemmGrid, 256, 0, stream>>>(abuf, W2, hbuf, N);
    agg_kernel<<<aggGrid, 256, 0, stream>>>(hbuf, offs, edges, b2, out, 0, N);
}

// Round 3
// 263.366 us; speedup vs baseline: 2.6139x; 1.6351x over previous
//
#include <hip/hip_runtime.h>
#include <hip/hip_bf16.h>

#define DFEAT 128

typedef __attribute__((ext_vector_type(8))) short short8;
typedef __attribute__((ext_vector_type(4))) float f32x4;

__device__ __forceinline__ ushort f2bf(float f) {
    uint u = __float_as_uint(f);
    u += 0x7FFF + ((u >> 16) & 1);   // round-to-nearest-even
    return (ushort)(u >> 16);
}
__device__ __forceinline__ float bf_lo(uint v) { return __uint_as_float(v << 16); }
__device__ __forceinline__ float bf_hi(uint v) { return __uint_as_float(v & 0xFFFF0000u); }

// ---------------- CSR build ----------------

// Histogram src (for norm) and dst (for CSR); capture per-edge rank within dst
// from the atomic's return value so fill needs no atomic.
__global__ void count_kernel(const int* __restrict__ EI, int* __restrict__ deg_src,
                             int* __restrict__ cnt_dst, int* __restrict__ erank, int nedges) {
    int e = blockIdx.x * blockDim.x + threadIdx.x;
    if (e >= nedges) return;
    int dst = EI[e];              // edge_index[0]
    int src = EI[nedges + e];     // edge_index[1]
    atomicAdd(&deg_src[src], 1);
    erank[e] = atomicAdd(&cnt_dst[dst], 1);
}

// Block-level inclusive scan of cnt into offs[g+1]; per-block total into bsums.
// Also computes dis[] = deg>0 ? rsqrt(deg) : 0 (fused to save a launch).
__global__ __launch_bounds__(1024) void scan1_kernel(const int* __restrict__ cnt,
                                                     int* __restrict__ offs,
                                                     int* __restrict__ bsums,
                                                     const int* __restrict__ deg,
                                                     float* __restrict__ dis, int n) {
    __shared__ int s[1024];
    int t = threadIdx.x;
    int g = blockIdx.x * 1024 + t;
    if (g < n) {
        int d = deg[g];
        dis[g] = (d > 0) ? rsqrtf((float)d) : 0.0f;
    }
    int v = (g < n) ? cnt[g] : 0;
    s[t] = v;
    __syncthreads();
    for (int off = 1; off < 1024; off <<= 1) {
        int add = (t >= off) ? s[t - off] : 0;
        __syncthreads();
        s[t] += add;
        __syncthreads();
    }
    if (g < n) offs[g + 1] = s[t];
    if (t == 1023) bsums[blockIdx.x] = s[1023];
}

__global__ void scan2_kernel(int* __restrict__ bsums, int nb) {
    int lane = threadIdx.x;  // blockDim = 64
    int v = (lane < nb) ? bsums[lane] : 0;
    for (int off = 1; off < 64; off <<= 1) {
        int t = __shfl_up(v, off);
        if (lane >= off) v += t;
    }
    int ex = __shfl_up(v, 1);
    if (lane == 0) ex = 0;
    if (lane < nb) bsums[lane] = ex;
}

__global__ __launch_bounds__(1024) void scan3_kernel(int* __restrict__ offs,
                                                     const int* __restrict__ bsums, int n) {
    int t = threadIdx.x;
    int b = blockIdx.x;
    int g = b * 1024 + t;
    int add = bsums[b];
    if (g < n) offs[g + 1] += add;
    if (b == 0 && t == 0) offs[0] = 0;
}

// Atomic-free fill: slot = offs[dst] + rank captured in count.
__global__ void fill_kernel(const int* __restrict__ EI, const int* __restrict__ offs,
                            const int* __restrict__ erank, const float* __restrict__ dis,
                            int2* __restrict__ edges, int nedges) {
    int e = blockIdx.x * blockDim.x + threadIdx.x;
    if (e >= nedges) return;
    int dst = EI[e];
    int src = EI[nedges + e];
    int idx = offs[dst] + erank[e];
    float nm = dis[src] * dis[dst];
    edges[idx] = make_int2(src, __float_as_int(nm));
}

// Convert W0,W1,W2 (f32 [k][n] row-major) -> Wtb bf16 [m][n][k] (transposed).
__global__ void prepw_kernel(const float* __restrict__ W0, const float* __restrict__ W1,
                             const float* __restrict__ W2, ushort* __restrict__ Wtb) {
    int i = blockIdx.x * 256 + threadIdx.x;   // [0, 3*16384)
    int m = i >> 14, r = i & 16383;
    int n = r >> 7, k = r & 127;
    const float* W = (m == 0) ? W0 : (m == 1) ? W1 : W2;
    Wtb[i] = f2bf(W[k * DFEAT + n]);
}

// ---------------- GEMM: Hb[N,128](bf16) = Xin[N,128] @ W ----------------
// MFMA 16x16x32 bf16. Block = 4 waves; wave w handles rows blk*64 + w*16 .. +15,
// all 128 output cols (8 n-tiles). Wt (transposed W, bf16) staged in LDS once,
// padded stride 136 (2-way bank conflicts only). No barriers in main loop.
// A-frag layout: row = lane&15, k = (lane>>4)*8 + j (contiguous in memory).
// B-frag layout: col = lane&15, k = (lane>>4)*8 + j (contiguous in Wt[n][k]).
// C/D layout:    col = lane&15, row = (lane>>4)*4 + reg.

template <int IN_F32>
__global__ __launch_bounds__(256) void gemm_mfma(const void* __restrict__ Xin,
                                                 const ushort* __restrict__ Wtb,
                                                 ushort* __restrict__ Hb, int nrows) {
    __shared__ ushort wlds[128 * 136];
    const int t = threadIdx.x;

    // stage Wt: 2048 chunks of 16B; 16 chunks per 128-elem row
    #pragma unroll
    for (int q = 0; q < 8; ++q) {
        int c = t + q * 256;
        int row = c >> 4, cr = c & 15;
        short8 v = *(const short8*)(Wtb + c * 8);
        *(short8*)(&wlds[row * 136 + cr * 8]) = v;
    }
    __syncthreads();

    const int lane = t & 63;
    const int r16 = lane & 15, g = lane >> 4;
    const int row = blockIdx.x * 64 + (t >> 6) * 16 + r16;
    const int srow = (row < nrows) ? row : (nrows - 1);

    // A fragments for the 4 k-chunks
    short8 a[4];
    if (IN_F32) {
        const float* X = (const float*)Xin;
        #pragma unroll
        for (int kc = 0; kc < 4; ++kc) {
            const float* p = X + (size_t)srow * DFEAT + kc * 32 + g * 8;
            float4 f0 = *(const float4*)p;
            float4 f1 = *(const float4*)(p + 4);
            short8 s;
            s[0] = (short)f2bf(f0.x); s[1] = (short)f2bf(f0.y);
            s[2] = (short)f2bf(f0.z); s[3] = (short)f2bf(f0.w);
            s[4] = (short)f2bf(f1.x); s[5] = (short)f2bf(f1.y);
            s[6] = (short)f2bf(f1.z); s[7] = (short)f2bf(f1.w);
            a[kc] = s;
        }
    } else {
        const ushort* X = (const ushort*)Xin;
        #pragma unroll
        for (int kc = 0; kc < 4; ++kc)
            a[kc] = *(const short8*)(X + (size_t)srow * DFEAT + kc * 32 + g * 8);
    }

    f32x4 acc[8];
    #pragma unroll
    for (int nt = 0; nt < 8; ++nt) acc[nt] = (f32x4){0.f, 0.f, 0.f, 0.f};

    #pragma unroll
    for (int kc = 0; kc < 4; ++kc) {
        #pragma unroll
        for (int nt = 0; nt < 8; ++nt) {
            short8 b = *(const short8*)(&wlds[(nt * 16 + r16) * 136 + kc * 32 + g * 8]);
            acc[nt] = __builtin_amdgcn_mfma_f32_16x16x32_bf16(a[kc], b, acc[nt], 0, 0, 0);
        }
    }

    const int orow_base = blockIdx.x * 64 + (t >> 6) * 16 + g * 4;
    #pragma unroll
    for (int nt = 0; nt < 8; ++nt) {
        #pragma unroll
        for (int r = 0; r < 4; ++r) {
            int orow = orow_base + r;
            if (orow < nrows)
                Hb[(size_t)orow * DFEAT + nt * 16 + r16] = f2bf(acc[nt][r]);
        }
    }
}

// ---------------- Aggregation: one wave per dst node, bf16 H ----------------
// Lane covers 2 feature cols (4B gather per lane = 256B per row, coalesced).

template <int RELU, int OUT_F32>
__global__ __launch_bounds__(256) void agg_kernel(const ushort* __restrict__ H,
                                                  const int* __restrict__ offs,
                                                  const int2* __restrict__ edges,
                                                  const float* __restrict__ bias,
                                                  void* __restrict__ OUT, int nnodes) {
    int node = blockIdx.x * 4 + (threadIdx.x >> 6);
    int lane = threadIdx.x & 63;
    if (node >= nnodes) return;
    int s = offs[node];
    int e = offs[node + 1];
    float ax = 0.f, ay = 0.f, bx = 0.f, by = 0.f;
    float cx = 0.f, cy = 0.f, dx = 0.f, dy = 0.f;
    int idx = s;
    for (; idx + 4 <= e; idx += 4) {
        int2 e0 = edges[idx];
        int2 e1 = edges[idx + 1];
        int2 e2 = edges[idx + 2];
        int2 e3 = edges[idx + 3];
        uint v0 = *(const uint*)(H + (size_t)e0.x * DFEAT + lane * 2);
        uint v1 = *(const uint*)(H + (size_t)e1.x * DFEAT + lane * 2);
        uint v2 = *(const uint*)(H + (size_t)e2.x * DFEAT + lane * 2);
        uint v3 = *(const uint*)(H + (size_t)e3.x * DFEAT + lane * 2);
        float n0 = __int_as_float(e0.y), n1 = __int_as_float(e1.y);
        float n2 = __int_as_float(e2.y), n3 = __int_as_float(e3.y);
        ax += n0 * bf_lo(v0); ay += n0 * bf_hi(v0);
        bx += n1 * bf_lo(v1); by += n1 * bf_hi(v1);
        cx += n2 * bf_lo(v2); cy += n2 * bf_hi(v2);
        dx += n3 * bf_lo(v3); dy += n3 * bf_hi(v3);
    }
    for (; idx < e; ++idx) {
        int2 e0 = edges[idx];
        float n0 = __int_as_float(e0.y);
        uint v0 = *(const uint*)(H + (size_t)e0.x * DFEAT + lane * 2);
        ax += n0 * bf_lo(v0); ay += n0 * bf_hi(v0);
    }
    ax += bx + cx + dx;
    ay += by + cy + dy;
    float2 b = *(const float2*)&bias[lane * 2];
    ax += b.x;
    ay += b.y;
    if (RELU) { ax = fmaxf(ax, 0.f); ay = fmaxf(ay, 0.f); }
    if (OUT_F32) {
        *(float2*)((float*)OUT + (size_t)node * DFEAT + lane * 2) = make_float2(ax, ay);
    } else {
        uint packed = (uint)f2bf(ax) | ((uint)f2bf(ay) << 16);
        *(uint*)((ushort*)OUT + (size_t)node * DFEAT + lane * 2) = packed;
    }
}

// ---------------- launch ----------------

extern "C" void kernel_launch(void* const* d_in, const int* in_sizes, int n_in,
                              void* d_out, int out_size, void* d_ws, size_t ws_size,
                              hipStream_t stream) {
    const float* x  = (const float*)d_in[0];
    const int*   EI = (const int*)d_in[1];
    const float* W0 = (const float*)d_in[2];
    const float* b0 = (const float*)d_in[3];
    const float* W1 = (const float*)d_in[4];
    const float* b1 = (const float*)d_in[5];
    const float* W2 = (const float*)d_in[6];
    const float* b2 = (const float*)d_in[7];
    float* out = (float*)d_out;

    const int N = in_sizes[0] / DFEAT;
    const int E = in_sizes[1] / 2;

    // workspace layout (256B aligned)
    char* w = (char*)d_ws;
    auto alloc = [&](size_t bytes) {
        void* p = (void*)w;
        w += (bytes + 255) & ~(size_t)255;
        return p;
    };
    int*    deg   = (int*)alloc((size_t)N * 4);
    int*    cnt   = (int*)alloc((size_t)N * 4);
    int*    offs  = (int*)alloc((size_t)(N + 1) * 4);
    int*    bsums = (int*)alloc(64 * 4);
    float*  dis   = (float*)alloc((size_t)N * 4);
    int*    erank = (int*)alloc((size_t)E * 4);
    int2*   edges = (int2*)alloc((size_t)E * 8);
    ushort* Wtb   = (ushort*)alloc((size_t)3 * DFEAT * DFEAT * 2);
    ushort* hbuf  = (ushort*)alloc((size_t)N * DFEAT * 2);
    ushort* abuf  = (ushort*)alloc((size_t)N * DFEAT * 2);

    // zero deg..cnt span in one memset (padding harmless)
    size_t zspan = (char*)cnt + (size_t)N * 4 - (char*)deg;
    hipMemsetAsync(deg, 0, zspan, stream);

    const int nb = (N + 1023) / 1024;

    prepw_kernel<<<(3 * DFEAT * DFEAT) / 256, 256, 0, stream>>>(W0, W1, W2, Wtb);
    count_kernel<<<(E + 255) / 256, 256, 0, stream>>>(EI, deg, cnt, erank, E);
    scan1_kernel<<<nb, 1024, 0, stream>>>(cnt, offs, bsums, deg, dis, N);
    scan2_kernel<<<1, 64, 0, stream>>>(bsums, nb);
    scan3_kernel<<<nb, 1024, 0, stream>>>(offs, bsums, N);
    fill_kernel<<<(E + 255) / 256, 256, 0, stream>>>(EI, offs, erank, dis, edges, E);

    const int gemmGrid = (N + 63) / 64;
    const int aggGrid  = (N + 3) / 4;

    // layer 0: x(f32) -> hbuf(bf16) -> abuf(bf16, relu)
    gemm_mfma<1><<<gemmGrid, 256, 0, stream>>>(x, Wtb, hbuf, N);
    agg_kernel<1, 0><<<aggGrid, 256, 0, stream>>>(hbuf, offs, edges, b0, abuf, N);
    // layer 1
    gemm_mfma<0><<<gemmGrid, 256, 0, stream>>>(abuf, Wtb + DFEAT * DFEAT, hbuf, N);
    agg_kernel<1, 0><<<aggGrid, 256, 0, stream>>>(hbuf, offs, edges, b1, abuf, N);
    // layer 2: -> d_out (f32, no relu)
    gemm_mfma<0><<<gemmGrid, 256, 0, stream>>>(abuf, Wtb + 2 * DFEAT * DFEAT, hbuf, N);
    agg_kernel<0, 1><<<aggGrid, 256, 0, stream>>>(hbuf, offs, edges, b2, out, N);
}

// Round 4
// 254.023 us; speedup vs baseline: 2.7100x; 1.0368x over previous
//
#include <hip/hip_runtime.h>
#include <hip/hip_bf16.h>

#define DFEAT 128

typedef __attribute__((ext_vector_type(8))) short short8;
typedef __attribute__((ext_vector_type(4))) float f32x4;

__device__ __forceinline__ ushort f2bf(float f) {
    uint u = __float_as_uint(f);
    u += 0x7FFF + ((u >> 16) & 1);   // round-to-nearest-even
    return (ushort)(u >> 16);
}
__device__ __forceinline__ float bf_lo(uint v) { return __uint_as_float(v << 16); }
__device__ __forceinline__ float bf_hi(uint v) { return __uint_as_float(v & 0xFFFF0000u); }

// ---------------- CSR build ----------------

// Histogram src (for norm) and dst (for CSR); capture per-edge rank within dst
// from the atomic's return value so fill needs no atomic.
__global__ void count_kernel(const int* __restrict__ EI, int* __restrict__ deg_src,
                             int* __restrict__ cnt_dst, int* __restrict__ erank, int nedges) {
    int e = blockIdx.x * blockDim.x + threadIdx.x;
    if (e >= nedges) return;
    int dst = EI[e];              // edge_index[0]
    int src = EI[nedges + e];     // edge_index[1]
    atomicAdd(&deg_src[src], 1);
    erank[e] = atomicAdd(&cnt_dst[dst], 1);
}

// Block-level inclusive scan of cnt into offs[g+1]; per-block total into bsums.
// Also computes dis[] = deg>0 ? rsqrt(deg) : 0 (fused to save a launch).
__global__ __launch_bounds__(1024) void scan1_kernel(const int* __restrict__ cnt,
                                                     int* __restrict__ offs,
                                                     int* __restrict__ bsums,
                                                     const int* __restrict__ deg,
                                                     float* __restrict__ dis, int n) {
    __shared__ int s[1024];
    int t = threadIdx.x;
    int g = blockIdx.x * 1024 + t;
    if (g < n) {
        int d = deg[g];
        dis[g] = (d > 0) ? rsqrtf((float)d) : 0.0f;
    }
    int v = (g < n) ? cnt[g] : 0;
    s[t] = v;
    __syncthreads();
    for (int off = 1; off < 1024; off <<= 1) {
        int add = (t >= off) ? s[t - off] : 0;
        __syncthreads();
        s[t] += add;
        __syncthreads();
    }
    if (g < n) offs[g + 1] = s[t];
    if (t == 1023) bsums[blockIdx.x] = s[1023];
}

// scan3 with fused block-sum scan: every block redundantly exclusive-scans
// bsums[0..nb) (nb <= 64) in its first wave, then adds to its slice.
__global__ __launch_bounds__(1024) void scan3_kernel(int* __restrict__ offs,
                                                     const int* __restrict__ bsums,
                                                     int n, int nb) {
    __shared__ int pre[64];
    int t = threadIdx.x;
    if (t < 64) {
        int v = (t < nb) ? bsums[t] : 0;
        for (int off = 1; off < 64; off <<= 1) {
            int u = __shfl_up(v, off);
            if (t >= off) v += u;
        }
        int ex = __shfl_up(v, 1);
        if (t == 0) ex = 0;
        pre[t] = ex;
    }
    __syncthreads();
    int add = pre[blockIdx.x];
    int g = blockIdx.x * 1024 + t;
    if (g < n) offs[g + 1] += add;
    if (blockIdx.x == 0 && t == 0) offs[0] = 0;
}

// Atomic-free fill: slot = offs[dst] + rank captured in count.
__global__ void fill_kernel(const int* __restrict__ EI, const int* __restrict__ offs,
                            const int* __restrict__ erank, const float* __restrict__ dis,
                            int2* __restrict__ edges, int nedges) {
    int e = blockIdx.x * blockDim.x + threadIdx.x;
    if (e >= nedges) return;
    int dst = EI[e];
    int src = EI[nedges + e];
    int idx = offs[dst] + erank[e];
    float nm = dis[src] * dis[dst];
    edges[idx] = make_int2(src, __float_as_int(nm));
}

// Convert W0,W1,W2 (f32 [k][n] row-major) -> Wtb bf16 [m][n][k] (transposed).
__global__ void prepw_kernel(const float* __restrict__ W0, const float* __restrict__ W1,
                             const float* __restrict__ W2, ushort* __restrict__ Wtb) {
    int i = blockIdx.x * 256 + threadIdx.x;   // [0, 3*16384)
    int m = i >> 14, r = i & 16383;
    int n = r >> 7, k = r & 127;
    const float* W = (m == 0) ? W0 : (m == 1) ? W1 : W2;
    Wtb[i] = f2bf(W[k * DFEAT + n]);
}

// ---------------- GEMM: Hb[N,128](bf16) = Xin[N,128] @ W ----------------
// MFMA 16x16x32 bf16; see R3 notes. 64 rows/block, Wt in LDS, no loop barriers.

template <int IN_F32>
__global__ __launch_bounds__(256) void gemm_mfma(const void* __restrict__ Xin,
                                                 const ushort* __restrict__ Wtb,
                                                 ushort* __restrict__ Hb, int nrows) {
    __shared__ ushort wlds[128 * 136];
    const int t = threadIdx.x;

    #pragma unroll
    for (int q = 0; q < 8; ++q) {
        int c = t + q * 256;
        int row = c >> 4, cr = c & 15;
        short8 v = *(const short8*)(Wtb + c * 8);
        *(short8*)(&wlds[row * 136 + cr * 8]) = v;
    }
    __syncthreads();

    const int lane = t & 63;
    const int r16 = lane & 15, g = lane >> 4;
    const int row = blockIdx.x * 64 + (t >> 6) * 16 + r16;
    const int srow = (row < nrows) ? row : (nrows - 1);

    short8 a[4];
    if (IN_F32) {
        const float* X = (const float*)Xin;
        #pragma unroll
        for (int kc = 0; kc < 4; ++kc) {
            const float* p = X + (size_t)srow * DFEAT + kc * 32 + g * 8;
            float4 f0 = *(const float4*)p;
            float4 f1 = *(const float4*)(p + 4);
            short8 s;
            s[0] = (short)f2bf(f0.x); s[1] = (short)f2bf(f0.y);
            s[2] = (short)f2bf(f0.z); s[3] = (short)f2bf(f0.w);
            s[4] = (short)f2bf(f1.x); s[5] = (short)f2bf(f1.y);
            s[6] = (short)f2bf(f1.z); s[7] = (short)f2bf(f1.w);
            a[kc] = s;
        }
    } else {
        const ushort* X = (const ushort*)Xin;
        #pragma unroll
        for (int kc = 0; kc < 4; ++kc)
            a[kc] = *(const short8*)(X + (size_t)srow * DFEAT + kc * 32 + g * 8);
    }

    f32x4 acc[8];
    #pragma unroll
    for (int nt = 0; nt < 8; ++nt) acc[nt] = (f32x4){0.f, 0.f, 0.f, 0.f};

    #pragma unroll
    for (int kc = 0; kc < 4; ++kc) {
        #pragma unroll
        for (int nt = 0; nt < 8; ++nt) {
            short8 b = *(const short8*)(&wlds[(nt * 16 + r16) * 136 + kc * 32 + g * 8]);
            acc[nt] = __builtin_amdgcn_mfma_f32_16x16x32_bf16(a[kc], b, acc[nt], 0, 0, 0);
        }
    }

    const int orow_base = blockIdx.x * 64 + (t >> 6) * 16 + g * 4;
    #pragma unroll
    for (int nt = 0; nt < 8; ++nt) {
        #pragma unroll
        for (int r = 0; r < 4; ++r) {
            int orow = orow_base + r;
            if (orow < nrows)
                Hb[(size_t)orow * DFEAT + nt * 16 + r16] = f2bf(acc[nt][r]);
        }
    }
}

// ---------------- Aggregation: one wave per dst node, 2 edges in parallel ----
// Lane l: half = l>>5, feature cols 4*(l&31)..+3 (uint2 = 4 bf16 = 8B per lane,
// 32 lanes cover the 256B row). Halves process alternating edges; unroll x2
// -> 4 edges in flight per wave. Cross-half combine via __shfl_xor(.,32).

template <int RELU, int OUT_F32>
__global__ __launch_bounds__(256) void agg_kernel(const ushort* __restrict__ H,
                                                  const int* __restrict__ offs,
                                                  const int2* __restrict__ edges,
                                                  const float* __restrict__ bias,
                                                  void* __restrict__ OUT, int nnodes) {
    int node = blockIdx.x * 4 + (threadIdx.x >> 6);
    if (node >= nnodes) return;
    int lane = threadIdx.x & 63;
    int half = lane >> 5;
    int l32 = lane & 31;
    int s = offs[node];
    int e = offs[node + 1];

    float a0 = 0.f, a1 = 0.f, a2 = 0.f, a3 = 0.f;
    float c0 = 0.f, c1 = 0.f, c2 = 0.f, c3 = 0.f;
    const ushort* __restrict__ Hp = H + l32 * 4;

    int i = s + half;
    for (; i + 2 < e; i += 4) {
        int2 er0 = edges[i];
        int2 er1 = edges[i + 2];
        uint2 v0 = *(const uint2*)(Hp + (size_t)er0.x * DFEAT);
        uint2 v1 = *(const uint2*)(Hp + (size_t)er1.x * DFEAT);
        float n0 = __int_as_float(er0.y);
        float n1 = __int_as_float(er1.y);
        a0 += n0 * bf_lo(v0.x); a1 += n0 * bf_hi(v0.x);
        a2 += n0 * bf_lo(v0.y); a3 += n0 * bf_hi(v0.y);
        c0 += n1 * bf_lo(v1.x); c1 += n1 * bf_hi(v1.x);
        c2 += n1 * bf_lo(v1.y); c3 += n1 * bf_hi(v1.y);
    }
    if (i < e) {
        int2 er0 = edges[i];
        uint2 v0 = *(const uint2*)(Hp + (size_t)er0.x * DFEAT);
        float n0 = __int_as_float(er0.y);
        a0 += n0 * bf_lo(v0.x); a1 += n0 * bf_hi(v0.x);
        a2 += n0 * bf_lo(v0.y); a3 += n0 * bf_hi(v0.y);
    }
    a0 += c0; a1 += c1; a2 += c2; a3 += c3;

    // combine the two halves (both end with the full sum)
    a0 += __shfl_xor(a0, 32);
    a1 += __shfl_xor(a1, 32);
    a2 += __shfl_xor(a2, 32);
    a3 += __shfl_xor(a3, 32);

    float4 b4 = *(const float4*)&bias[l32 * 4];
    a0 += b4.x; a1 += b4.y; a2 += b4.z; a3 += b4.w;
    if (RELU) {
        a0 = fmaxf(a0, 0.f); a1 = fmaxf(a1, 0.f);
        a2 = fmaxf(a2, 0.f); a3 = fmaxf(a3, 0.f);
    }
    if (half == 0) {
        if (OUT_F32) {
            *(float4*)((float*)OUT + (size_t)node * DFEAT + l32 * 4) =
                make_float4(a0, a1, a2, a3);
        } else {
            uint2 p;
            p.x = (uint)f2bf(a0) | ((uint)f2bf(a1) << 16);
            p.y = (uint)f2bf(a2) | ((uint)f2bf(a3) << 16);
            *(uint2*)((ushort*)OUT + (size_t)node * DFEAT + l32 * 4) = p;
        }
    }
}

// ---------------- launch ----------------

extern "C" void kernel_launch(void* const* d_in, const int* in_sizes, int n_in,
                              void* d_out, int out_size, void* d_ws, size_t ws_size,
                              hipStream_t stream) {
    const float* x  = (const float*)d_in[0];
    const int*   EI = (const int*)d_in[1];
    const float* W0 = (const float*)d_in[2];
    const float* b0 = (const float*)d_in[3];
    const float* W1 = (const float*)d_in[4];
    const float* b1 = (const float*)d_in[5];
    const float* W2 = (const float*)d_in[6];
    const float* b2 = (const float*)d_in[7];
    float* out = (float*)d_out;

    const int N = in_sizes[0] / DFEAT;
    const int E = in_sizes[1] / 2;

    // workspace layout (256B aligned)
    char* w = (char*)d_ws;
    auto alloc = [&](size_t bytes) {
        void* p = (void*)w;
        w += (bytes + 255) & ~(size_t)255;
        return p;
    };
    int*    deg   = (int*)alloc((size_t)N * 4);
    int*    cnt   = (int*)alloc((size_t)N * 4);
    int*    offs  = (int*)alloc((size_t)(N + 1) * 4);
    int*    bsums = (int*)alloc(64 * 4);
    float*  dis   = (float*)alloc((size_t)N * 4);
    int*    erank = (int*)alloc((size_t)E * 4);
    int2*   edges = (int2*)alloc((size_t)E * 8);
    ushort* Wtb   = (ushort*)alloc((size_t)3 * DFEAT * DFEAT * 2);
    ushort* hbuf  = (ushort*)alloc((size_t)N * DFEAT * 2);
    ushort* abuf  = (ushort*)alloc((size_t)N * DFEAT * 2);

    // zero deg..cnt span in one memset (padding harmless)
    size_t zspan = (char*)cnt + (size_t)N * 4 - (char*)deg;
    hipMemsetAsync(deg, 0, zspan, stream);

    const int nb = (N + 1023) / 1024;

    prepw_kernel<<<(3 * DFEAT * DFEAT) / 256, 256, 0, stream>>>(W0, W1, W2, Wtb);
    count_kernel<<<(E + 255) / 256, 256, 0, stream>>>(EI, deg, cnt, erank, E);
    scan1_kernel<<<nb, 1024, 0, stream>>>(cnt, offs, bsums, deg, dis, N);
    scan3_kernel<<<nb, 1024, 0, stream>>>(offs, bsums, N, nb);
    fill_kernel<<<(E + 255) / 256, 256, 0, stream>>>(EI, offs, erank, dis, edges, E);

    const int gemmGrid = (N + 63) / 64;
    const int aggGrid  = (N + 3) / 4;

    // layer 0: x(f32) -> hbuf(bf16) -> abuf(bf16, relu)
    gemm_mfma<1><<<gemmGrid, 256, 0, stream>>>(x, Wtb, hbuf, N);
    agg_kernel<1, 0><<<aggGrid, 256, 0, stream>>>(hbuf, offs, edges, b0, abuf, N);
    // layer 1
    gemm_mfma<0><<<gemmGrid, 256, 0, stream>>>(abuf, Wtb + DFEAT * DFEAT, hbuf, N);
    agg_kernel<1, 0><<<aggGrid, 256, 0, stream>>>(hbuf, offs, edges, b1, abuf, N);
    // layer 2: -> d_out (f32, no relu)
    gemm_mfma<0><<<gemmGrid, 256, 0, stream>>>(abuf, Wtb + 2 * DFEAT * DFEAT, hbuf, N);
    agg_kernel<0, 1><<<aggGrid, 256, 0, stream>>>(hbuf, offs, edges, b2, out, N);
}

// Round 5
// 241.293 us; speedup vs baseline: 2.8530x; 1.0528x over previous
//
#include <hip/hip_runtime.h>
#include <hip/hip_bf16.h>

#define DFEAT 128
#define RSPLIT 16   // node-range splits
#define SSPLIT 16   // edge-slice splits

typedef __attribute__((ext_vector_type(8))) short short8;
typedef __attribute__((ext_vector_type(4))) float f32x4;

__device__ __forceinline__ ushort f2bf(float f) {
    uint u = __float_as_uint(f);
    u += 0x7FFF + ((u >> 16) & 1);   // round-to-nearest-even
    return (ushort)(u >> 16);
}
__device__ __forceinline__ float bf_lo(uint v) { return __uint_as_float(v << 16); }
__device__ __forceinline__ float bf_hi(uint v) { return __uint_as_float(v & 0xFFFF0000u); }

// ---------------- CSR build (zero global atomics) ----------------

// Block (r,s): LDS-privatized dst & src histograms for node range r over edge
// slice s. Captures per-edge rank within (dst, slice) from the LDS atomic.
__global__ __launch_bounds__(512) void histrank_kernel(const int* __restrict__ EI,
                                                       int* __restrict__ cnt_part,
                                                       int* __restrict__ deg_part,
                                                       int* __restrict__ erank,
                                                       int nedges, int nnodes,
                                                       int range, int slice) {
    extern __shared__ int lds[];      // [0,range): dst hist, [range,2*range): src hist
    int* hd = lds;
    int* hs = lds + range;
    const int r = blockIdx.x & (RSPLIT - 1);
    const int s = blockIdx.x / RSPLIT;
    const int base = r * range;
    for (int i = threadIdx.x; i < 2 * range; i += 512) lds[i] = 0;
    __syncthreads();

    const int e0 = s * slice;
    const int e1 = min(nedges, e0 + slice);
    for (int e = e0 + threadIdx.x; e < e1; e += 512) {
        int dst = EI[e];
        int src = EI[nedges + e];
        unsigned ud = (unsigned)(dst - base);
        unsigned us = (unsigned)(src - base);
        if (ud < (unsigned)range) erank[e] = atomicAdd(&hd[ud], 1);
        if (us < (unsigned)range) atomicAdd(&hs[us], 1);
    }
    __syncthreads();

    for (int i = threadIdx.x; i < range; i += 512) {
        int node = base + i;
        if (node < nnodes) {
            cnt_part[s * nnodes + node] = hd[i];
            deg_part[s * nnodes + node] = hs[i];
        }
    }
}

// Per node: sum 16 cnt partials (writing the exclusive slice-prefix) and 16 deg
// partials (-> dis), then block-scan the node counts into offs[g+1] + bsums.
__global__ __launch_bounds__(1024) void scan1_kernel(const int* __restrict__ cnt_part,
                                                     const int* __restrict__ deg_part,
                                                     int* __restrict__ sprefix,
                                                     int* __restrict__ offs,
                                                     int* __restrict__ bsums,
                                                     float* __restrict__ dis, int n) {
    __shared__ int sm[1024];
    int t = threadIdx.x;
    int g = blockIdx.x * 1024 + t;
    int c = 0;
    if (g < n) {
        int d = 0;
        #pragma unroll
        for (int s = 0; s < SSPLIT; ++s) {
            sprefix[s * n + g] = c;
            c += cnt_part[s * n + g];
            d += deg_part[s * n + g];
        }
        dis[g] = (d > 0) ? rsqrtf((float)d) : 0.0f;
    }
    sm[t] = c;
    __syncthreads();
    for (int off = 1; off < 1024; off <<= 1) {
        int add = (t >= off) ? sm[t - off] : 0;
        __syncthreads();
        sm[t] += add;
        __syncthreads();
    }
    if (g < n) offs[g + 1] = sm[t];
    if (t == 1023) bsums[blockIdx.x] = sm[1023];
}

// scan3 with fused block-sum scan: every block redundantly exclusive-scans
// bsums[0..nb) (nb <= 64) in its first wave, then adds to its slice.
__global__ __launch_bounds__(1024) void scan3_kernel(int* __restrict__ offs,
                                                     const int* __restrict__ bsums,
                                                     int n, int nb) {
    __shared__ int pre[64];
    int t = threadIdx.x;
    if (t < 64) {
        int v = (t < nb) ? bsums[t] : 0;
        for (int off = 1; off < 64; off <<= 1) {
            int u = __shfl_up(v, off);
            if (t >= off) v += u;
        }
        int ex = __shfl_up(v, 1);
        if (t == 0) ex = 0;
        pre[t] = ex;
    }
    __syncthreads();
    int add = pre[blockIdx.x];
    int g = blockIdx.x * 1024 + t;
    if (g < n) offs[g + 1] += add;
    if (blockIdx.x == 0 && t == 0) offs[0] = 0;
}

// Atomic-free fill: slot = offs[dst] + sprefix[slice][dst] + local rank.
__global__ void fill_kernel(const int* __restrict__ EI, const int* __restrict__ offs,
                            const int* __restrict__ erank, const int* __restrict__ sprefix,
                            const float* __restrict__ dis, int2* __restrict__ edges,
                            int nedges, int nnodes, int slice) {
    int e = blockIdx.x * blockDim.x + threadIdx.x;
    if (e >= nedges) return;
    int dst = EI[e];
    int src = EI[nedges + e];
    int s = e / slice;
    int idx = offs[dst] + sprefix[s * nnodes + dst] + erank[e];
    float nm = dis[src] * dis[dst];
    edges[idx] = make_int2(src, __float_as_int(nm));
}

// Convert W0,W1,W2 (f32 [k][n] row-major) -> Wtb bf16 [m][n][k] (transposed).
__global__ void prepw_kernel(const float* __restrict__ W0, const float* __restrict__ W1,
                             const float* __restrict__ W2, ushort* __restrict__ Wtb) {
    int i = blockIdx.x * 256 + threadIdx.x;   // [0, 3*16384)
    int m = i >> 14, r = i & 16383;
    int n = r >> 7, k = r & 127;
    const float* W = (m == 0) ? W0 : (m == 1) ? W1 : W2;
    Wtb[i] = f2bf(W[k * DFEAT + n]);
}

// ---------------- GEMM: Hb[N,128](bf16) = Xin[N,128] @ W ----------------
// MFMA 16x16x32 bf16. 64 rows/block, Wt in LDS, no loop barriers.

template <int IN_F32>
__global__ __launch_bounds__(256) void gemm_mfma(const void* __restrict__ Xin,
                                                 const ushort* __restrict__ Wtb,
                                                 ushort* __restrict__ Hb, int nrows) {
    __shared__ ushort wlds[128 * 136];
    const int t = threadIdx.x;

    #pragma unroll
    for (int q = 0; q < 8; ++q) {
        int c = t + q * 256;
        int row = c >> 4, cr = c & 15;
        short8 v = *(const short8*)(Wtb + c * 8);
        *(short8*)(&wlds[row * 136 + cr * 8]) = v;
    }
    __syncthreads();

    const int lane = t & 63;
    const int r16 = lane & 15, g = lane >> 4;
    const int row = blockIdx.x * 64 + (t >> 6) * 16 + r16;
    const int srow = (row < nrows) ? row : (nrows - 1);

    short8 a[4];
    if (IN_F32) {
        const float* X = (const float*)Xin;
        #pragma unroll
        for (int kc = 0; kc < 4; ++kc) {
            const float* p = X + (size_t)srow * DFEAT + kc * 32 + g * 8;
            float4 f0 = *(const float4*)p;
            float4 f1 = *(const float4*)(p + 4);
            short8 s;
            s[0] = (short)f2bf(f0.x); s[1] = (short)f2bf(f0.y);
            s[2] = (short)f2bf(f0.z); s[3] = (short)f2bf(f0.w);
            s[4] = (short)f2bf(f1.x); s[5] = (short)f2bf(f1.y);
            s[6] = (short)f2bf(f1.z); s[7] = (short)f2bf(f1.w);
            a[kc] = s;
        }
    } else {
        const ushort* X = (const ushort*)Xin;
        #pragma unroll
        for (int kc = 0; kc < 4; ++kc)
            a[kc] = *(const short8*)(X + (size_t)srow * DFEAT + kc * 32 + g * 8);
    }

    f32x4 acc[8];
    #pragma unroll
    for (int nt = 0; nt < 8; ++nt) acc[nt] = (f32x4){0.f, 0.f, 0.f, 0.f};

    #pragma unroll
    for (int kc = 0; kc < 4; ++kc) {
        #pragma unroll
        for (int nt = 0; nt < 8; ++nt) {
            short8 b = *(const short8*)(&wlds[(nt * 16 + r16) * 136 + kc * 32 + g * 8]);
            acc[nt] = __builtin_amdgcn_mfma_f32_16x16x32_bf16(a[kc], b, acc[nt], 0, 0, 0);
        }
    }

    const int orow_base = blockIdx.x * 64 + (t >> 6) * 16 + g * 4;
    #pragma unroll
    for (int nt = 0; nt < 8; ++nt) {
        #pragma unroll
        for (int r = 0; r < 4; ++r) {
            int orow = orow_base + r;
            if (orow < nrows)
                Hb[(size_t)orow * DFEAT + nt * 16 + r16] = f2bf(acc[nt][r]);
        }
    }
}

// ---------------- Aggregation: one wave per dst node, 2 edges in parallel ----

template <int RELU, int OUT_F32>
__global__ __launch_bounds__(256) void agg_kernel(const ushort* __restrict__ H,
                                                  const int* __restrict__ offs,
                                                  const int2* __restrict__ edges,
                                                  const float* __restrict__ bias,
                                                  void* __restrict__ OUT, int nnodes) {
    int node = blockIdx.x * 4 + (threadIdx.x >> 6);
    if (node >= nnodes) return;
    int lane = threadIdx.x & 63;
    int half = lane >> 5;
    int l32 = lane & 31;
    int s = offs[node];
    int e = offs[node + 1];

    float a0 = 0.f, a1 = 0.f, a2 = 0.f, a3 = 0.f;
    float c0 = 0.f, c1 = 0.f, c2 = 0.f, c3 = 0.f;
    const ushort* __restrict__ Hp = H + l32 * 4;

    int i = s + half;
    for (; i + 2 < e; i += 4) {
        int2 er0 = edges[i];
        int2 er1 = edges[i + 2];
        uint2 v0 = *(const uint2*)(Hp + (size_t)er0.x * DFEAT);
        uint2 v1 = *(const uint2*)(Hp + (size_t)er1.x * DFEAT);
        float n0 = __int_as_float(er0.y);
        float n1 = __int_as_float(er1.y);
        a0 += n0 * bf_lo(v0.x); a1 += n0 * bf_hi(v0.x);
        a2 += n0 * bf_lo(v0.y); a3 += n0 * bf_hi(v0.y);
        c0 += n1 * bf_lo(v1.x); c1 += n1 * bf_hi(v1.x);
        c2 += n1 * bf_lo(v1.y); c3 += n1 * bf_hi(v1.y);
    }
    if (i < e) {
        int2 er0 = edges[i];
        uint2 v0 = *(const uint2*)(Hp + (size_t)er0.x * DFEAT);
        float n0 = __int_as_float(er0.y);
        a0 += n0 * bf_lo(v0.x); a1 += n0 * bf_hi(v0.x);
        a2 += n0 * bf_lo(v0.y); a3 += n0 * bf_hi(v0.y);
    }
    a0 += c0; a1 += c1; a2 += c2; a3 += c3;

    a0 += __shfl_xor(a0, 32);
    a1 += __shfl_xor(a1, 32);
    a2 += __shfl_xor(a2, 32);
    a3 += __shfl_xor(a3, 32);

    float4 b4 = *(const float4*)&bias[l32 * 4];
    a0 += b4.x; a1 += b4.y; a2 += b4.z; a3 += b4.w;
    if (RELU) {
        a0 = fmaxf(a0, 0.f); a1 = fmaxf(a1, 0.f);
        a2 = fmaxf(a2, 0.f); a3 = fmaxf(a3, 0.f);
    }
    if (half == 0) {
        if (OUT_F32) {
            *(float4*)((float*)OUT + (size_t)node * DFEAT + l32 * 4) =
                make_float4(a0, a1, a2, a3);
        } else {
            uint2 p;
            p.x = (uint)f2bf(a0) | ((uint)f2bf(a1) << 16);
            p.y = (uint)f2bf(a2) | ((uint)f2bf(a3) << 16);
            *(uint2*)((ushort*)OUT + (size_t)node * DFEAT + l32 * 4) = p;
        }
    }
}

// ---------------- launch ----------------

extern "C" void kernel_launch(void* const* d_in, const int* in_sizes, int n_in,
                              void* d_out, int out_size, void* d_ws, size_t ws_size,
                              hipStream_t stream) {
    const float* x  = (const float*)d_in[0];
    const int*   EI = (const int*)d_in[1];
    const float* W0 = (const float*)d_in[2];
    const float* b0 = (const float*)d_in[3];
    const float* W1 = (const float*)d_in[4];
    const float* b1 = (const float*)d_in[5];
    const float* W2 = (const float*)d_in[6];
    const float* b2 = (const float*)d_in[7];
    float* out = (float*)d_out;

    const int N = in_sizes[0] / DFEAT;
    const int E = in_sizes[1] / 2;
    const int range = (N + RSPLIT - 1) / RSPLIT;
    const int slice = (E + SSPLIT - 1) / SSPLIT;

    // workspace layout (256B aligned)
    char* w = (char*)d_ws;
    auto alloc = [&](size_t bytes) {
        void* p = (void*)w;
        w += (bytes + 255) & ~(size_t)255;
        return p;
    };
    int*    offs  = (int*)alloc((size_t)(N + 1) * 4);
    int*    bsums = (int*)alloc(64 * 4);
    float*  dis   = (float*)alloc((size_t)N * 4);
    int2*   edges = (int2*)alloc((size_t)E * 8);
    ushort* Wtb   = (ushort*)alloc((size_t)3 * DFEAT * DFEAT * 2);
    ushort* hbuf  = (ushort*)alloc((size_t)N * DFEAT * 2);
    ushort* abuf  = (ushort*)alloc((size_t)N * DFEAT * 2);

    // CSR-build scratch aliased onto hbuf/abuf (dead before gemm/agg run):
    int* cnt_part = (int*)hbuf;                              // SSPLIT*N ints
    int* deg_part = (int*)hbuf + (size_t)SSPLIT * N;         // SSPLIT*N ints
    int* sprefix  = (int*)abuf;                              // SSPLIT*N ints
    int* erank    = (int*)abuf + (size_t)SSPLIT * N;         // E ints

    const int nb = (N + 1023) / 1024;

    prepw_kernel<<<(3 * DFEAT * DFEAT) / 256, 256, 0, stream>>>(W0, W1, W2, Wtb);
    histrank_kernel<<<RSPLIT * SSPLIT, 512, 2 * range * 4, stream>>>(
        EI, cnt_part, deg_part, erank, E, N, range, slice);
    scan1_kernel<<<nb, 1024, 0, stream>>>(cnt_part, deg_part, sprefix, offs, bsums, dis, N);
    scan3_kernel<<<nb, 1024, 0, stream>>>(offs, bsums, N, nb);
    fill_kernel<<<(E + 255) / 256, 256, 0, stream>>>(EI, offs, erank, sprefix, dis,
                                                     edges, E, N, slice);

    const int gemmGrid = (N + 63) / 64;
    const int aggGrid  = (N + 3) / 4;

    // layer 0: x(f32) -> hbuf(bf16) -> abuf(bf16, relu)
    gemm_mfma<1><<<gemmGrid, 256, 0, stream>>>(x, Wtb, hbuf, N);
    agg_kernel<1, 0><<<aggGrid, 256, 0, stream>>>(hbuf, offs, edges, b0, abuf, N);
    // layer 1
    gemm_mfma<0><<<gemmGrid, 256, 0, stream>>>(abuf, Wtb + DFEAT * DFEAT, hbuf, N);
    agg_kernel<1, 0><<<aggGrid, 256, 0, stream>>>(hbuf, offs, edges, b1, abuf, N);
    // layer 2: -> d_out (f32, no relu)
    gemm_mfma<0><<<gemmGrid, 256, 0, stream>>>(abuf, Wtb + 2 * DFEAT * DFEAT, hbuf, N);
    agg_kernel<0, 1><<<aggGrid, 256, 0, stream>>>(hbuf, offs, edges, b2, out, N);
}

// Round 6
// 221.379 us; speedup vs baseline: 3.1097x; 1.0900x over previous
//
#include <hip/hip_runtime.h>
#include <hip/hip_bf16.h>

#define DFEAT 128
#define RSPLIT 16   // node-range splits (LDS histogram size = 2*ceil(N/16) ints)
#define SSPLIT 64   // edge-slice splits (grid = 1024 blocks -> 4 blocks/CU)

typedef __attribute__((ext_vector_type(8))) short short8;
typedef __attribute__((ext_vector_type(4))) float f32x4;

__device__ __forceinline__ ushort f2bf(float f) {
    uint u = __float_as_uint(f);
    u += 0x7FFF + ((u >> 16) & 1);   // round-to-nearest-even
    return (ushort)(u >> 16);
}
__device__ __forceinline__ float bf_lo(uint v) { return __uint_as_float(v << 16); }
__device__ __forceinline__ float bf_hi(uint v) { return __uint_as_float(v & 0xFFFF0000u); }

// ---------------- CSR build (zero global atomics) ----------------

// Block (r,s): LDS-privatized dst & src histograms for node range r over edge
// slice s. Captures per-edge rank within (dst, slice) from the LDS atomic.
__global__ __launch_bounds__(512) void histrank_kernel(const int* __restrict__ EI,
                                                       int* __restrict__ cnt_part,
                                                       int* __restrict__ deg_part,
                                                       int* __restrict__ erank,
                                                       int nedges, int nnodes,
                                                       int range, int slice) {
    extern __shared__ int lds[];      // [0,range): dst hist, [range,2*range): src hist
    int* hd = lds;
    int* hs = lds + range;
    const int r = blockIdx.x & (RSPLIT - 1);
    const int s = blockIdx.x / RSPLIT;
    const int base = r * range;
    for (int i = threadIdx.x; i < 2 * range; i += 512) lds[i] = 0;
    __syncthreads();

    const int e0 = s * slice;
    const int e1 = min(nedges, e0 + slice);
    for (int e = e0 + threadIdx.x; e < e1; e += 512) {
        int dst = EI[e];
        int src = EI[nedges + e];
        unsigned ud = (unsigned)(dst - base);
        unsigned us = (unsigned)(src - base);
        if (ud < (unsigned)range) erank[e] = atomicAdd(&hd[ud], 1);
        if (us < (unsigned)range) atomicAdd(&hs[us], 1);
    }
    __syncthreads();

    for (int i = threadIdx.x; i < range; i += 512) {
        int node = base + i;
        if (node < nnodes) {
            cnt_part[s * nnodes + node] = hd[i];
            deg_part[s * nnodes + node] = hs[i];
        }
    }
}

// Per node: in-place exclusive prefix over the SSPLIT cnt partials (cnt_part
// becomes the slice-prefix table), sum deg partials -> dis, then block-scan
// the node totals into offs[g+1] + bsums.
__global__ __launch_bounds__(1024) void scan1_kernel(int* __restrict__ cnt_part,
                                                     const int* __restrict__ deg_part,
                                                     int* __restrict__ offs,
                                                     int* __restrict__ bsums,
                                                     float* __restrict__ dis, int n) {
    __shared__ int sm[1024];
    int t = threadIdx.x;
    int g = blockIdx.x * 1024 + t;
    int c = 0;
    if (g < n) {
        int d = 0;
        #pragma unroll
        for (int s = 0; s < SSPLIT; ++s) {
            int v = cnt_part[s * n + g];
            cnt_part[s * n + g] = c;      // exclusive slice prefix, in place
            c += v;
            d += deg_part[s * n + g];
        }
        dis[g] = (d > 0) ? rsqrtf((float)d) : 0.0f;
    }
    sm[t] = c;
    __syncthreads();
    for (int off = 1; off < 1024; off <<= 1) {
        int add = (t >= off) ? sm[t - off] : 0;
        __syncthreads();
        sm[t] += add;
        __syncthreads();
    }
    if (g < n) offs[g + 1] = sm[t];
    if (t == 1023) bsums[blockIdx.x] = sm[1023];
}

// scan3 with fused block-sum scan: every block redundantly exclusive-scans
// bsums[0..nb) (nb <= 64) in its first wave, then adds to its slice.
__global__ __launch_bounds__(1024) void scan3_kernel(int* __restrict__ offs,
                                                     const int* __restrict__ bsums,
                                                     int n, int nb) {
    __shared__ int pre[64];
    int t = threadIdx.x;
    if (t < 64) {
        int v = (t < nb) ? bsums[t] : 0;
        for (int off = 1; off < 64; off <<= 1) {
            int u = __shfl_up(v, off);
            if (t >= off) v += u;
        }
        int ex = __shfl_up(v, 1);
        if (t == 0) ex = 0;
        pre[t] = ex;
    }
    __syncthreads();
    int add = pre[blockIdx.x];
    int g = blockIdx.x * 1024 + t;
    if (g < n) offs[g + 1] += add;
    if (blockIdx.x == 0 && t == 0) offs[0] = 0;
}

// Atomic-free fill: slot = offs[dst] + sprefix[slice][dst] + local rank.
__global__ void fill_kernel(const int* __restrict__ EI, const int* __restrict__ offs,
                            const int* __restrict__ erank, const int* __restrict__ sprefix,
                            const float* __restrict__ dis, int2* __restrict__ edges,
                            int nedges, int nnodes, int slice) {
    int e = blockIdx.x * blockDim.x + threadIdx.x;
    if (e >= nedges) return;
    int dst = EI[e];
    int src = EI[nedges + e];
    int s = e / slice;
    int idx = offs[dst] + sprefix[s * nnodes + dst] + erank[e];
    float nm = dis[src] * dis[dst];
    edges[idx] = make_int2(src, __float_as_int(nm));
}

// Convert W0,W1,W2 (f32 [k][n] row-major) -> Wtb bf16 [m][n][k] (transposed).
__global__ void prepw_kernel(const float* __restrict__ W0, const float* __restrict__ W1,
                             const float* __restrict__ W2, ushort* __restrict__ Wtb) {
    int i = blockIdx.x * 256 + threadIdx.x;   // [0, 3*16384)
    int m = i >> 14, r = i & 16383;
    int n = r >> 7, k = r & 127;
    const float* W = (m == 0) ? W0 : (m == 1) ? W1 : W2;
    Wtb[i] = f2bf(W[k * DFEAT + n]);
}

// ---------------- GEMM: Hb[N,128](bf16) = Xin[N,128] @ W ----------------
// MFMA 16x16x32 bf16. 64 rows/block, Wt in LDS, no loop barriers.

template <int IN_F32>
__global__ __launch_bounds__(256) void gemm_mfma(const void* __restrict__ Xin,
                                                 const ushort* __restrict__ Wtb,
                                                 ushort* __restrict__ Hb, int nrows) {
    __shared__ ushort wlds[128 * 136];
    const int t = threadIdx.x;

    #pragma unroll
    for (int q = 0; q < 8; ++q) {
        int c = t + q * 256;
        int row = c >> 4, cr = c & 15;
        short8 v = *(const short8*)(Wtb + c * 8);
        *(short8*)(&wlds[row * 136 + cr * 8]) = v;
    }
    __syncthreads();

    const int lane = t & 63;
    const int r16 = lane & 15, g = lane >> 4;
    const int row = blockIdx.x * 64 + (t >> 6) * 16 + r16;
    const int srow = (row < nrows) ? row : (nrows - 1);

    short8 a[4];
    if (IN_F32) {
        const float* X = (const float*)Xin;
        #pragma unroll
        for (int kc = 0; kc < 4; ++kc) {
            const float* p = X + (size_t)srow * DFEAT + kc * 32 + g * 8;
            float4 f0 = *(const float4*)p;
            float4 f1 = *(const float4*)(p + 4);
            short8 s;
            s[0] = (short)f2bf(f0.x); s[1] = (short)f2bf(f0.y);
            s[2] = (short)f2bf(f0.z); s[3] = (short)f2bf(f0.w);
            s[4] = (short)f2bf(f1.x); s[5] = (short)f2bf(f1.y);
            s[6] = (short)f2bf(f1.z); s[7] = (short)f2bf(f1.w);
            a[kc] = s;
        }
    } else {
        const ushort* X = (const ushort*)Xin;
        #pragma unroll
        for (int kc = 0; kc < 4; ++kc)
            a[kc] = *(const short8*)(X + (size_t)srow * DFEAT + kc * 32 + g * 8);
    }

    f32x4 acc[8];
    #pragma unroll
    for (int nt = 0; nt < 8; ++nt) acc[nt] = (f32x4){0.f, 0.f, 0.f, 0.f};

    #pragma unroll
    for (int kc = 0; kc < 4; ++kc) {
        #pragma unroll
        for (int nt = 0; nt < 8; ++nt) {
            short8 b = *(const short8*)(&wlds[(nt * 16 + r16) * 136 + kc * 32 + g * 8]);
            acc[nt] = __builtin_amdgcn_mfma_f32_16x16x32_bf16(a[kc], b, acc[nt], 0, 0, 0);
        }
    }

    const int orow_base = blockIdx.x * 64 + (t >> 6) * 16 + g * 4;
    #pragma unroll
    for (int nt = 0; nt < 8; ++nt) {
        #pragma unroll
        for (int r = 0; r < 4; ++r) {
            int orow = orow_base + r;
            if (orow < nrows)
                Hb[(size_t)orow * DFEAT + nt * 16 + r16] = f2bf(acc[nt][r]);
        }
    }
}

// ---------------- Aggregation: one wave per dst node, 2 edges in parallel ----

template <int RELU, int OUT_F32>
__global__ __launch_bounds__(256) void agg_kernel(const ushort* __restrict__ H,
                                                  const int* __restrict__ offs,
                                                  const int2* __restrict__ edges,
                                                  const float* __restrict__ bias,
                                                  void* __restrict__ OUT, int nnodes) {
    int node = blockIdx.x * 4 + (threadIdx.x >> 6);
    if (node >= nnodes) return;
    int lane = threadIdx.x & 63;
    int half = lane >> 5;
    int l32 = lane & 31;
    int s = offs[node];
    int e = offs[node + 1];

    float a0 = 0.f, a1 = 0.f, a2 = 0.f, a3 = 0.f;
    float c0 = 0.f, c1 = 0.f, c2 = 0.f, c3 = 0.f;
    const ushort* __restrict__ Hp = H + l32 * 4;

    int i = s + half;
    for (; i + 2 < e; i += 4) {
        int2 er0 = edges[i];
        int2 er1 = edges[i + 2];
        uint2 v0 = *(const uint2*)(Hp + (size_t)er0.x * DFEAT);
        uint2 v1 = *(const uint2*)(Hp + (size_t)er1.x * DFEAT);
        float n0 = __int_as_float(er0.y);
        float n1 = __int_as_float(er1.y);
        a0 += n0 * bf_lo(v0.x); a1 += n0 * bf_hi(v0.x);
        a2 += n0 * bf_lo(v0.y); a3 += n0 * bf_hi(v0.y);
        c0 += n1 * bf_lo(v1.x); c1 += n1 * bf_hi(v1.x);
        c2 += n1 * bf_lo(v1.y); c3 += n1 * bf_hi(v1.y);
    }
    if (i < e) {
        int2 er0 = edges[i];
        uint2 v0 = *(const uint2*)(Hp + (size_t)er0.x * DFEAT);
        float n0 = __int_as_float(er0.y);
        a0 += n0 * bf_lo(v0.x); a1 += n0 * bf_hi(v0.x);
        a2 += n0 * bf_lo(v0.y); a3 += n0 * bf_hi(v0.y);
    }
    a0 += c0; a1 += c1; a2 += c2; a3 += c3;

    a0 += __shfl_xor(a0, 32);
    a1 += __shfl_xor(a1, 32);
    a2 += __shfl_xor(a2, 32);
    a3 += __shfl_xor(a3, 32);

    float4 b4 = *(const float4*)&bias[l32 * 4];
    a0 += b4.x; a1 += b4.y; a2 += b4.z; a3 += b4.w;
    if (RELU) {
        a0 = fmaxf(a0, 0.f); a1 = fmaxf(a1, 0.f);
        a2 = fmaxf(a2, 0.f); a3 = fmaxf(a3, 0.f);
    }
    if (half == 0) {
        if (OUT_F32) {
            *(float4*)((float*)OUT + (size_t)node * DFEAT + l32 * 4) =
                make_float4(a0, a1, a2, a3);
        } else {
            uint2 p;
            p.x = (uint)f2bf(a0) | ((uint)f2bf(a1) << 16);
            p.y = (uint)f2bf(a2) | ((uint)f2bf(a3) << 16);
            *(uint2*)((ushort*)OUT + (size_t)node * DFEAT + l32 * 4) = p;
        }
    }
}

// ---------------- launch ----------------

extern "C" void kernel_launch(void* const* d_in, const int* in_sizes, int n_in,
                              void* d_out, int out_size, void* d_ws, size_t ws_size,
                              hipStream_t stream) {
    const float* x  = (const float*)d_in[0];
    const int*   EI = (const int*)d_in[1];
    const float* W0 = (const float*)d_in[2];
    const float* b0 = (const float*)d_in[3];
    const float* W1 = (const float*)d_in[4];
    const float* b1 = (const float*)d_in[5];
    const float* W2 = (const float*)d_in[6];
    const float* b2 = (const float*)d_in[7];
    float* out = (float*)d_out;

    const int N = in_sizes[0] / DFEAT;
    const int E = in_sizes[1] / 2;
    const int range = (N + RSPLIT - 1) / RSPLIT;
    const int slice = (E + SSPLIT - 1) / SSPLIT;

    // workspace layout (256B aligned)
    char* w = (char*)d_ws;
    auto alloc = [&](size_t bytes) {
        void* p = (void*)w;
        w += (bytes + 255) & ~(size_t)255;
        return p;
    };
    int*    offs  = (int*)alloc((size_t)(N + 1) * 4);
    int*    bsums = (int*)alloc(64 * 4);
    float*  dis   = (float*)alloc((size_t)N * 4);
    int*    erank = (int*)alloc((size_t)E * 4);
    int2*   edges = (int2*)alloc((size_t)E * 8);
    ushort* Wtb   = (ushort*)alloc((size_t)3 * DFEAT * DFEAT * 2);
    ushort* hbuf  = (ushort*)alloc((size_t)N * DFEAT * 2);   // >= SSPLIT*N*4 bytes
    ushort* abuf  = (ushort*)alloc((size_t)N * DFEAT * 2);   // >= SSPLIT*N*4 bytes

    // CSR-build scratch aliased onto hbuf/abuf (dead before gemm/agg run):
    // SSPLIT*N ints == N*DFEAT bf16 exactly (64*4 == 128*2).
    int* cnt_part = (int*)hbuf;   // becomes slice-prefix table after scan1
    int* deg_part = (int*)abuf;

    const int nb = (N + 1023) / 1024;

    prepw_kernel<<<(3 * DFEAT * DFEAT) / 256, 256, 0, stream>>>(W0, W1, W2, Wtb);
    histrank_kernel<<<RSPLIT * SSPLIT, 512, 2 * range * 4, stream>>>(
        EI, cnt_part, deg_part, erank, E, N, range, slice);
    scan1_kernel<<<nb, 1024, 0, stream>>>(cnt_part, deg_part, offs, bsums, dis, N);
    scan3_kernel<<<nb, 1024, 0, stream>>>(offs, bsums, N, nb);
    fill_kernel<<<(E + 255) / 256, 256, 0, stream>>>(EI, offs, erank, cnt_part, dis,
                                                     edges, E, N, slice);

    const int gemmGrid = (N + 63) / 64;
    const int aggGrid  = (N + 3) / 4;

    // layer 0: x(f32) -> hbuf(bf16) -> abuf(bf16, relu)
    gemm_mfma<1><<<gemmGrid, 256, 0, stream>>>(x, Wtb, hbuf, N);
    agg_kernel<1, 0><<<aggGrid, 256, 0, stream>>>(hbuf, offs, edges, b0, abuf, N);
    // layer 1
    gemm_mfma<0><<<gemmGrid, 256, 0, stream>>>(abuf, Wtb + DFEAT * DFEAT, hbuf, N);
    agg_kernel<1, 0><<<aggGrid, 256, 0, stream>>>(hbuf, offs, edges, b1, abuf, N);
    // layer 2: -> d_out (f32, no relu)
    gemm_mfma<0><<<gemmGrid, 256, 0, stream>>>(abuf, Wtb + 2 * DFEAT * DFEAT, hbuf, N);
    agg_kernel<0, 1><<<aggGrid, 256, 0, stream>>>(hbuf, offs, edges, b2, out, N);
}

// Round 7
// 205.920 us; speedup vs baseline: 3.3431x; 1.0751x over previous
//
#include <hip/hip_runtime.h>
#include <hip/hip_bf16.h>

#define DFEAT 128
#define RSPLIT 8    // node-range splits (LDS hist = 2*ceil(N/8)*4 B = 50 KB)
#define SSPLIT 64   // edge-slice splits (grid = 512 blocks, fully resident)

typedef __attribute__((ext_vector_type(8))) short short8;
typedef __attribute__((ext_vector_type(4))) float f32x4;

__device__ __forceinline__ ushort f2bf(float f) {
    uint u = __float_as_uint(f);
    u += 0x7FFF + ((u >> 16) & 1);   // round-to-nearest-even
    return (ushort)(u >> 16);
}
__device__ __forceinline__ float bf_lo(uint v) { return __uint_as_float(v << 16); }
__device__ __forceinline__ float bf_hi(uint v) { return __uint_as_float(v & 0xFFFF0000u); }

// ---------------- CSR build (zero global atomics) ----------------

// Block (r,s): LDS-privatized dst & src histograms for node range r over edge
// slice s. Captures per-edge rank within (dst, slice) from the LDS atomic.
__global__ __launch_bounds__(512) void histrank_kernel(const int* __restrict__ EI,
                                                       int* __restrict__ cnt_part,
                                                       int* __restrict__ deg_part,
                                                       int* __restrict__ erank,
                                                       int nedges, int nnodes,
                                                       int range, int slice) {
    extern __shared__ int lds[];      // [0,range): dst hist, [range,2*range): src hist
    int* hd = lds;
    int* hs = lds + range;
    const int r = blockIdx.x & (RSPLIT - 1);
    const int s = blockIdx.x / RSPLIT;
    const int base = r * range;
    for (int i = threadIdx.x; i < 2 * range; i += 512) lds[i] = 0;
    __syncthreads();

    const int e0 = s * slice;
    const int e1 = min(nedges, e0 + slice);
    for (int e = e0 + threadIdx.x; e < e1; e += 512) {
        int dst = EI[e];
        int src = EI[nedges + e];
        unsigned ud = (unsigned)(dst - base);
        unsigned us = (unsigned)(src - base);
        if (ud < (unsigned)range) erank[e] = atomicAdd(&hd[ud], 1);
        if (us < (unsigned)range) atomicAdd(&hs[us], 1);
    }
    __syncthreads();

    for (int i = threadIdx.x; i < range; i += 512) {
        int node = base + i;
        if (node < nnodes) {
            cnt_part[s * nnodes + node] = hd[i];
            deg_part[s * nnodes + node] = hs[i];
        }
    }
}

// Per node: in-place exclusive prefix over the SSPLIT cnt partials (cnt_part
// becomes the slice-prefix table), sum deg partials -> dis, then block-scan
// the node totals into offs[g+1] + bsums.
__global__ __launch_bounds__(1024) void scan1_kernel(int* __restrict__ cnt_part,
                                                     const int* __restrict__ deg_part,
                                                     int* __restrict__ offs,
                                                     int* __restrict__ bsums,
                                                     float* __restrict__ dis, int n) {
    __shared__ int sm[1024];
    int t = threadIdx.x;
    int g = blockIdx.x * 1024 + t;
    int c = 0;
    if (g < n) {
        int d = 0;
        #pragma unroll
        for (int s = 0; s < SSPLIT; ++s) {
            int v = cnt_part[s * n + g];
            cnt_part[s * n + g] = c;      // exclusive slice prefix, in place
            c += v;
            d += deg_part[s * n + g];
        }
        dis[g] = (d > 0) ? rsqrtf((float)d) : 0.0f;
    }
    sm[t] = c;
    __syncthreads();
    for (int off = 1; off < 1024; off <<= 1) {
        int add = (t >= off) ? sm[t - off] : 0;
        __syncthreads();
        sm[t] += add;
        __syncthreads();
    }
    if (g < n) offs[g + 1] = sm[t];
    if (t == 1023) bsums[blockIdx.x] = sm[1023];
}

// scan3 with fused block-sum scan: every block redundantly exclusive-scans
// bsums[0..nb) (nb <= 64) in its first wave, then adds to its slice.
__global__ __launch_bounds__(1024) void scan3_kernel(int* __restrict__ offs,
                                                     const int* __restrict__ bsums,
                                                     int n, int nb) {
    __shared__ int pre[64];
    int t = threadIdx.x;
    if (t < 64) {
        int v = (t < nb) ? bsums[t] : 0;
        for (int off = 1; off < 64; off <<= 1) {
            int u = __shfl_up(v, off);
            if (t >= off) v += u;
        }
        int ex = __shfl_up(v, 1);
        if (t == 0) ex = 0;
        pre[t] = ex;
    }
    __syncthreads();
    int add = pre[blockIdx.x];
    int g = blockIdx.x * 1024 + t;
    if (g < n) offs[g + 1] += add;
    if (blockIdx.x == 0 && t == 0) offs[0] = 0;
}

// Atomic-free fill: slot = offs[dst] + sprefix[slice][dst] + local rank.
// Stores src only (norm is folded into gemm epilogue / agg epilogue).
__global__ void fill_kernel(const int* __restrict__ EI, const int* __restrict__ offs,
                            const int* __restrict__ erank, const int* __restrict__ sprefix,
                            int* __restrict__ esrc, int nedges, int nnodes, int slice) {
    int e = blockIdx.x * blockDim.x + threadIdx.x;
    if (e >= nedges) return;
    int dst = EI[e];
    int src = EI[nedges + e];
    int s = e / slice;
    int idx = offs[dst] + sprefix[s * nnodes + dst] + erank[e];
    esrc[idx] = src;
}

// Convert W0,W1,W2 (f32 [k][n] row-major) -> Wtb bf16 [m][n][k] (transposed).
__global__ void prepw_kernel(const float* __restrict__ W0, const float* __restrict__ W1,
                             const float* __restrict__ W2, ushort* __restrict__ Wtb) {
    int i = blockIdx.x * 256 + threadIdx.x;   // [0, 3*16384)
    int m = i >> 14, r = i & 16383;
    int n = r >> 7, k = r & 127;
    const float* W = (m == 0) ? W0 : (m == 1) ? W1 : W2;
    Wtb[i] = f2bf(W[k * DFEAT + n]);
}

// ---------------- GEMM: Hd[N,128](bf16) = dis[r] * (Xin[N,128] @ W) --------
// MFMA 16x16x32 bf16. 128 rows/block (4 waves x 2 row-tiles), Wt in LDS,
// one ds_read_b128 feeds 2 MFMAs (B-register reuse across row-tiles).

template <int IN_F32>
__global__ __launch_bounds__(256) void gemm_mfma(const void* __restrict__ Xin,
                                                 const ushort* __restrict__ Wtb,
                                                 const float* __restrict__ dis,
                                                 ushort* __restrict__ Hb, int nrows) {
    __shared__ ushort wlds[128 * 136];
    const int t = threadIdx.x;

    #pragma unroll
    for (int q = 0; q < 8; ++q) {
        int c = t + q * 256;
        int row = c >> 4, cr = c & 15;
        short8 v = *(const short8*)(Wtb + c * 8);
        *(short8*)(&wlds[row * 136 + cr * 8]) = v;
    }

    const int lane = t & 63;
    const int r16 = lane & 15, g = lane >> 4;
    const int wv = t >> 6;
    const int rbase = blockIdx.x * 128 + wv * 16;

    // A fragments for both row-tiles (global loads overlap LDS staging)
    short8 a[2][4];
    #pragma unroll
    for (int rt = 0; rt < 2; ++rt) {
        int row = rbase + rt * 64 + r16;
        int srow = (row < nrows) ? row : (nrows - 1);
        if (IN_F32) {
            const float* X = (const float*)Xin;
            #pragma unroll
            for (int kc = 0; kc < 4; ++kc) {
                const float* p = X + (size_t)srow * DFEAT + kc * 32 + g * 8;
                float4 f0 = *(const float4*)p;
                float4 f1 = *(const float4*)(p + 4);
                short8 sv;
                sv[0] = (short)f2bf(f0.x); sv[1] = (short)f2bf(f0.y);
                sv[2] = (short)f2bf(f0.z); sv[3] = (short)f2bf(f0.w);
                sv[4] = (short)f2bf(f1.x); sv[5] = (short)f2bf(f1.y);
                sv[6] = (short)f2bf(f1.z); sv[7] = (short)f2bf(f1.w);
                a[rt][kc] = sv;
            }
        } else {
            const ushort* X = (const ushort*)Xin;
            #pragma unroll
            for (int kc = 0; kc < 4; ++kc)
                a[rt][kc] = *(const short8*)(X + (size_t)srow * DFEAT + kc * 32 + g * 8);
        }
    }
    __syncthreads();

    f32x4 acc[2][8];
    #pragma unroll
    for (int rt = 0; rt < 2; ++rt)
        #pragma unroll
        for (int nt = 0; nt < 8; ++nt) acc[rt][nt] = (f32x4){0.f, 0.f, 0.f, 0.f};

    #pragma unroll
    for (int kc = 0; kc < 4; ++kc) {
        #pragma unroll
        for (int nt = 0; nt < 8; ++nt) {
            short8 b = *(const short8*)(&wlds[(nt * 16 + r16) * 136 + kc * 32 + g * 8]);
            acc[0][nt] = __builtin_amdgcn_mfma_f32_16x16x32_bf16(a[0][kc], b, acc[0][nt], 0, 0, 0);
            acc[1][nt] = __builtin_amdgcn_mfma_f32_16x16x32_bf16(a[1][kc], b, acc[1][nt], 0, 0, 0);
        }
    }

    #pragma unroll
    for (int rt = 0; rt < 2; ++rt) {
        const int orow_base = rbase + rt * 64 + g * 4;
        #pragma unroll
        for (int r = 0; r < 4; ++r) {
            int orow = orow_base + r;
            if (orow < nrows) {
                float d = dis[orow];
                #pragma unroll
                for (int nt = 0; nt < 8; ++nt)
                    Hb[(size_t)orow * DFEAT + nt * 16 + r16] = f2bf(acc[rt][nt][r] * d);
            }
        }
    }
}

// ------- Aggregation: one wave per dst node, quarter-wave per edge ---------
// Lane l: quarter q = l>>4, feats 8*(l&15)..+7 (uint4 = 8 bf16 = 16B/lane,
// 16 lanes cover the 256B row). Quarters process edges i ≡ q (mod 4);
// unroll x2 -> 8 gathers in flight per wave. Reduce via shfl_xor 16,32.
// Epilogue: out = dis[dst]*sum + bias.

template <int RELU, int OUT_F32>
__global__ __launch_bounds__(256) void agg_kernel(const ushort* __restrict__ H,
                                                  const int* __restrict__ offs,
                                                  const int* __restrict__ esrc,
                                                  const float* __restrict__ dis,
                                                  const float* __restrict__ bias,
                                                  void* __restrict__ OUT, int nnodes) {
    int node = blockIdx.x * 4 + (threadIdx.x >> 6);
    if (node >= nnodes) return;
    int lane = threadIdx.x & 63;
    int q = lane >> 4;
    int l16 = lane & 15;
    int s = offs[node];
    int e = offs[node + 1];

    float a0 = 0.f, a1 = 0.f, a2 = 0.f, a3 = 0.f;
    float a4 = 0.f, a5 = 0.f, a6 = 0.f, a7 = 0.f;
    float c0 = 0.f, c1 = 0.f, c2 = 0.f, c3 = 0.f;
    float c4 = 0.f, c5 = 0.f, c6 = 0.f, c7 = 0.f;
    const ushort* __restrict__ Hp = H + l16 * 8;

    int i = s + q;
    for (; i + 4 < e; i += 8) {
        int s0 = esrc[i];
        int s1 = esrc[i + 4];
        uint4 v0 = *(const uint4*)(Hp + (size_t)s0 * DFEAT);
        uint4 v1 = *(const uint4*)(Hp + (size_t)s1 * DFEAT);
        a0 += bf_lo(v0.x); a1 += bf_hi(v0.x);
        a2 += bf_lo(v0.y); a3 += bf_hi(v0.y);
        a4 += bf_lo(v0.z); a5 += bf_hi(v0.z);
        a6 += bf_lo(v0.w); a7 += bf_hi(v0.w);
        c0 += bf_lo(v1.x); c1 += bf_hi(v1.x);
        c2 += bf_lo(v1.y); c3 += bf_hi(v1.y);
        c4 += bf_lo(v1.z); c5 += bf_hi(v1.z);
        c6 += bf_lo(v1.w); c7 += bf_hi(v1.w);
    }
    if (i < e) {
        int s0 = esrc[i];
        uint4 v0 = *(const uint4*)(Hp + (size_t)s0 * DFEAT);
        a0 += bf_lo(v0.x); a1 += bf_hi(v0.x);
        a2 += bf_lo(v0.y); a3 += bf_hi(v0.y);
        a4 += bf_lo(v0.z); a5 += bf_hi(v0.z);
        a6 += bf_lo(v0.w); a7 += bf_hi(v0.w);
    }
    a0 += c0; a1 += c1; a2 += c2; a3 += c3;
    a4 += c4; a5 += c5; a6 += c6; a7 += c7;

    a0 += __shfl_xor(a0, 16); a1 += __shfl_xor(a1, 16);
    a2 += __shfl_xor(a2, 16); a3 += __shfl_xor(a3, 16);
    a4 += __shfl_xor(a4, 16); a5 += __shfl_xor(a5, 16);
    a6 += __shfl_xor(a6, 16); a7 += __shfl_xor(a7, 16);
    a0 += __shfl_xor(a0, 32); a1 += __shfl_xor(a1, 32);
    a2 += __shfl_xor(a2, 32); a3 += __shfl_xor(a3, 32);
    a4 += __shfl_xor(a4, 32); a5 += __shfl_xor(a5, 32);
    a6 += __shfl_xor(a6, 32); a7 += __shfl_xor(a7, 32);

    float dn = dis[node];
    float4 b0 = *(const float4*)&bias[l16 * 8];
    float4 b1 = *(const float4*)&bias[l16 * 8 + 4];
    float r0 = dn * a0 + b0.x, r1 = dn * a1 + b0.y;
    float r2 = dn * a2 + b0.z, r3 = dn * a3 + b0.w;
    float r4 = dn * a4 + b1.x, r5 = dn * a5 + b1.y;
    float r6 = dn * a6 + b1.z, r7 = dn * a7 + b1.w;
    if (RELU) {
        r0 = fmaxf(r0, 0.f); r1 = fmaxf(r1, 0.f);
        r2 = fmaxf(r2, 0.f); r3 = fmaxf(r3, 0.f);
        r4 = fmaxf(r4, 0.f); r5 = fmaxf(r5, 0.f);
        r6 = fmaxf(r6, 0.f); r7 = fmaxf(r7, 0.f);
    }
    if (q == 0) {
        if (OUT_F32) {
            float* o = (float*)OUT + (size_t)node * DFEAT + l16 * 8;
            *(float4*)o = make_float4(r0, r1, r2, r3);
            *(float4*)(o + 4) = make_float4(r4, r5, r6, r7);
        } else {
            uint4 p;
            p.x = (uint)f2bf(r0) | ((uint)f2bf(r1) << 16);
            p.y = (uint)f2bf(r2) | ((uint)f2bf(r3) << 16);
            p.z = (uint)f2bf(r4) | ((uint)f2bf(r5) << 16);
            p.w = (uint)f2bf(r6) | ((uint)f2bf(r7) << 16);
            *(uint4*)((ushort*)OUT + (size_t)node * DFEAT + l16 * 8) = p;
        }
    }
}

// ---------------- launch ----------------

extern "C" void kernel_launch(void* const* d_in, const int* in_sizes, int n_in,
                              void* d_out, int out_size, void* d_ws, size_t ws_size,
                              hipStream_t stream) {
    const float* x  = (const float*)d_in[0];
    const int*   EI = (const int*)d_in[1];
    const float* W0 = (const float*)d_in[2];
    const float* b0 = (const float*)d_in[3];
    const float* W1 = (const float*)d_in[4];
    const float* b1 = (const float*)d_in[5];
    const float* W2 = (const float*)d_in[6];
    const float* b2 = (const float*)d_in[7];
    float* out = (float*)d_out;

    const int N = in_sizes[0] / DFEAT;
    const int E = in_sizes[1] / 2;
    const int range = (N + RSPLIT - 1) / RSPLIT;
    const int slice = (E + SSPLIT - 1) / SSPLIT;

    // workspace layout (256B aligned)
    char* w = (char*)d_ws;
    auto alloc = [&](size_t bytes) {
        void* p = (void*)w;
        w += (bytes + 255) & ~(size_t)255;
        return p;
    };
    int*    offs  = (int*)alloc((size_t)(N + 1) * 4);
    int*    bsums = (int*)alloc(64 * 4);
    float*  dis   = (float*)alloc((size_t)N * 4);
    int*    erank = (int*)alloc((size_t)E * 4);
    int*    esrc  = (int*)alloc((size_t)E * 4);
    ushort* Wtb   = (ushort*)alloc((size_t)3 * DFEAT * DFEAT * 2);
    ushort* hbuf  = (ushort*)alloc((size_t)N * DFEAT * 2);   // == SSPLIT*N*4 bytes
    ushort* abuf  = (ushort*)alloc((size_t)N * DFEAT * 2);   // == SSPLIT*N*4 bytes

    // CSR-build scratch aliased onto hbuf/abuf (dead before gemm/agg run):
    // SSPLIT*N ints == N*DFEAT bf16 exactly (64*4 == 128*2).
    int* cnt_part = (int*)hbuf;   // becomes slice-prefix table after scan1
    int* deg_part = (int*)abuf;

    const int nb = (N + 1023) / 1024;

    prepw_kernel<<<(3 * DFEAT * DFEAT) / 256, 256, 0, stream>>>(W0, W1, W2, Wtb);
    histrank_kernel<<<RSPLIT * SSPLIT, 512, 2 * range * 4, stream>>>(
        EI, cnt_part, deg_part, erank, E, N, range, slice);
    scan1_kernel<<<nb, 1024, 0, stream>>>(cnt_part, deg_part, offs, bsums, dis, N);
    scan3_kernel<<<nb, 1024, 0, stream>>>(offs, bsums, N, nb);
    fill_kernel<<<(E + 255) / 256, 256, 0, stream>>>(EI, offs, erank, cnt_part,
                                                     esrc, E, N, slice);

    const int gemmGrid = (N + 127) / 128;
    const int aggGrid  = (N + 3) / 4;

    // layer 0: x(f32) -> hbuf(bf16, dis-scaled) -> abuf(bf16, relu)
    gemm_mfma<1><<<gemmGrid, 256, 0, stream>>>(x, Wtb, dis, hbuf, N);
    agg_kernel<1, 0><<<aggGrid, 256, 0, stream>>>(hbuf, offs, esrc, dis, b0, abuf, N);
    // layer 1
    gemm_mfma<0><<<gemmGrid, 256, 0, stream>>>(abuf, Wtb + DFEAT * DFEAT, dis, hbuf, N);
    agg_kernel<1, 0><<<aggGrid, 256, 0, stream>>>(hbuf, offs, esrc, dis, b1, abuf, N);
    // layer 2: -> d_out (f32, no relu)
    gemm_mfma<0><<<gemmGrid, 256, 0, stream>>>(abuf, Wtb + 2 * DFEAT * DFEAT, dis, hbuf, N);
    agg_kernel<0, 1><<<aggGrid, 256, 0, stream>>>(hbuf, offs, esrc, dis, b2, out, N);
}